// Round 1
// baseline (316.550 us; speedup 1.0000x reference)
//
#include <hip/hip_runtime.h>

#define N_NODES 100000
#define N_EDGES 1000000
#define DEG_CAP 64
#define OVF_CAP 4096
#define RSTRIDE 100352   // N_NODES rounded up to 512

typedef __attribute__((ext_vector_type(8))) short bf16x8;
typedef __attribute__((ext_vector_type(4))) float f32x4;

__device__ __forceinline__ unsigned short f2bf(float f) {
    unsigned u = __float_as_uint(f);
    return (unsigned short)((u + 0x7FFF + ((u >> 16) & 1)) >> 16);
}
__device__ __forceinline__ float bf2f(unsigned short b) {
    return __uint_as_float(((unsigned)b) << 16);
}
__device__ __forceinline__ float bflo(unsigned u) {   // low bf16 of a dword
    return __uint_as_float(u << 16);
}
__device__ __forceinline__ float bfhi(unsigned u) {   // high bf16 of a dword
    return __uint_as_float(u & 0xffff0000u);
}

// ws layout (4B units):
//   counts_r : int [0,        802816)     8 replicas x RSTRIDE
//   prefs_r  : int [802816,  1605632)    node-relative replica prefix
//   counts   : int [1605632, 1705984)
//   pos16    : u16 [1705984, 2205984)    1M u16 = (replica<<13)|pos
//   ovfc     : int [2205984]
//   cursor   : int [2205985]             CSR allocation cursor
//   ovf      : int [2206048, 2214240)
//   Bf1      : s16 [2214240, 2230624)    32768 halfs (frag-ordered hi/lo)
//   Bf2      : s16 [2230624, 2247008)
//   nodeBase : int [2247008, 2347008)    CSR base per node
//   csr      : int [2347008, 3447008)    <= ~1M neighbor ids (compact)
//   xb       : u16 [8647008, 11847008)   N*64 bf16
//   mean1    : f32 [11847008, 18247008)  N*64; reused as p_bf after l1
//   h        : f32 [18247008, 31047008)  N*128
//   q        : f32 [31047008, 37447008)  N*64

// Merged init + weight-split + x->bf16 (grid-stride style, one launch).
__global__ __launch_bounds__(256) void prep_kernel(
        const float4* __restrict__ x4, ushort4* __restrict__ xb4,
        const float* __restrict__ W1l, const float* __restrict__ W1r,
        const float* __restrict__ W2l, const float* __restrict__ W2r,
        short* __restrict__ Bf1, short* __restrict__ Bf2,
        int4* __restrict__ counts_r4, int* __restrict__ ovfc,
        int* __restrict__ cursor) {
    int i = blockIdx.x * blockDim.x + threadIdx.x;
    if (i < (8 * RSTRIDE) / 4) counts_r4[i] = make_int4(0, 0, 0, 0);
    if (i == 0) { *ovfc = 0; *cursor = 0; }
    if (i < 32768) {
        int g = i >> 14;
        int e = i & 16383;
        int k = e >> 7;
        int n = e & 127;
        float v;
        if (g == 0) v = (k < 64) ? W1l[k * 128 + n] : W1r[(k - 64) * 128 + n];
        else        v = (n < 64) ? W2l[k * 64 + n]  : W2r[k * 64 + (n - 64)];
        unsigned u = __float_as_uint(v);
        unsigned hb = u >> 16;
        float vh = __uint_as_float(hb << 16);
        unsigned lb = __float_as_uint(v - vh) >> 16;
        int c = n >> 4, kc = k >> 5;
        int lane = (((k >> 3) & 3) << 4) | (n & 15);
        int j = k & 7;
        short* base = g ? Bf2 : Bf1;
        base[((c * 4 + kc) * 2 + 0) * 512 + lane * 8 + j] = (short)hb;
        base[((c * 4 + kc) * 2 + 1) * 512 + lane * 8 + j] = (short)lb;
    }
    if (i < N_NODES * 16) {
        float4 v = x4[i];
        ushort4 o;
        o.x = f2bf(v.x); o.y = f2bf(v.y); o.z = f2bf(v.z); o.w = f2bf(v.w);
        xb4[i] = o;
    }
}

// Phase 1: replicated histogram. Replica = ACTUAL XCD id (s_getreg).
// KEY: workgroup-scope atomic -> global_atomic_add WITHOUT sc1 -> RMW
// executes in the local XCD's L2 (replica lines are touched by exactly
// one XCD, so this is race-free; cross-kernel visibility comes from the
// dispatch-boundary release/acquire L2 flush the pipeline already relies
// on for prep's zero-stores). Device-scope (sc1) atomics were executing
// at the memory-side point (~10 RMW/cy chip-wide; 32B/atomic WRITE_SIZE).
__global__ __launch_bounds__(256) void hist_kernel(
        const int* __restrict__ ei, int* __restrict__ counts_r,
        unsigned short* __restrict__ pos16) {
    int e = blockIdx.x * blockDim.x + threadIdx.x;
    if (e >= N_EDGES) return;
    unsigned xcc;
    asm volatile("s_getreg_b32 %0, hwreg(HW_REG_XCC_ID)" : "=s"(xcc));
    int r = xcc & 7;
    int d = ei[N_EDGES + e];
    int p = __hip_atomic_fetch_add(&counts_r[r * RSTRIDE + d], 1,
                                   __ATOMIC_RELAXED,
                                   __HIP_MEMORY_SCOPE_WORKGROUP);
    if (p > 8191) p = 8191;
    pos16[e] = (unsigned short)((r << 13) | p);
}

// Phase 2: per-node prefix over the 8 replicas + CSR segment allocation.
// Wave-aggregated cursor bump (1 device-scope atomic per 64 nodes).
// prefs_r stores NODE-RELATIVE replica prefixes; nodeBase the CSR base.
__global__ __launch_bounds__(256) void scan_kernel(
        const int* __restrict__ counts_r, int* __restrict__ prefs_r,
        int* __restrict__ counts, int* __restrict__ nodeBase,
        int* __restrict__ cursor) {
    int d = blockIdx.x * blockDim.x + threadIdx.x;
    int l = threadIdx.x & 63;
    bool valid = d < N_NODES;
    int pre[8];
    int total = 0;
    if (valid) {
#pragma unroll
        for (int r = 0; r < 8; ++r) {
            pre[r] = total;
            total += counts_r[r * RSTRIDE + d];
        }
    }
    int alloc = valid ? min(total, DEG_CAP) : 0;
    // wave inclusive scan of alloc
    int pref = alloc;
#pragma unroll
    for (int ofs = 1; ofs < 64; ofs <<= 1) {
        int y = __shfl_up(pref, ofs);
        if (l >= ofs) pref += y;
    }
    int wtotal = __shfl(pref, 63);
    int excl = pref - alloc;
    int base = 0;
    if (l == 0) base = atomicAdd(cursor, wtotal);   // device scope: cross-XCD
    base = __shfl(base, 0);
    int myBase = base + excl;
    if (valid) {
        counts[d] = total;
        nodeBase[d] = myBase;
#pragma unroll
        for (int r = 0; r < 8; ++r) prefs_r[r * RSTRIDE + d] = pre[r];
    }
}

// Phase 3: atomic-free CSR fill; scatter target is a <=4MB region (L2
// resident) instead of the 25.6MB padded table. Overflow funnel kept.
__global__ __launch_bounds__(256) void fill_kernel(
        const int* __restrict__ ei, const unsigned short* __restrict__ pos16,
        const int* __restrict__ prefs_r, const int* __restrict__ nodeBase,
        int* __restrict__ csr, int* __restrict__ ovfc, int* __restrict__ ovf) {
    int e = blockIdx.x * blockDim.x + threadIdx.x;
    if (e >= N_EDGES) return;
    int s = ei[e];
    int d = ei[N_EDGES + e];
    unsigned pk = pos16[e];
    int r = pk >> 13;
    int p = pk & 8191;
    int rel = prefs_r[r * RSTRIDE + d] + p;   // node-relative position
    if (p < 8191 && rel < DEG_CAP) {
        csr[nodeBase[d] + rel] = s;
    } else {
        int o = atomicAdd(ovfc, 1);
        if (o < OVF_CAP) { ovf[o * 2] = s; ovf[o * 2 + 1] = d; }
    }
}

// One wave per node. Lane l: neighbor subgroup l>>4, features (l&15)*4..+3.
// One dwordx2 load covers 4 bf16 features of one neighbor; 4 subgroups ->
// 4 neighbor rows per load instruction. Butterfly-reduce across subgroups.
// Writes the MEAN (fp32). CSR: only dcap ids are loaded per node.
__global__ __launch_bounds__(256) void gather_bf_kernel(
        const unsigned short* __restrict__ feat, const int* __restrict__ counts,
        const int* __restrict__ nodeBase, const int* __restrict__ csr,
        float* __restrict__ agg) {
    int wid = blockIdx.x * 4 + (threadIdx.x >> 6);
    int l = threadIdx.x & 63;
    if (wid >= N_NODES) return;
    int deg = counts[wid];
    int dcap = min(deg, DEG_CAP);
    int base = nodeBase[wid];
    int ids = (l < dcap) ? csr[base + l] : 0;
    const int grp = l >> 4;
    const int fb = (l & 15) * 4;
    float s0 = 0.f, s1 = 0.f, s2 = 0.f, s3 = 0.f;
    int j = 0;
    for (; j + 8 <= dcap; j += 8) {   // grp<=3 -> both neighbors in-range
        int sA = __shfl(ids, j + grp);
        int sB = __shfl(ids, j + 4 + grp);
        uint2 uA = *(const uint2*)(feat + sA * 64 + fb);
        uint2 uB = *(const uint2*)(feat + sB * 64 + fb);
        s0 += bflo(uA.x) + bflo(uB.x);
        s1 += bfhi(uA.x) + bfhi(uB.x);
        s2 += bflo(uA.y) + bflo(uB.y);
        s3 += bfhi(uA.y) + bfhi(uB.y);
    }
    for (; j < dcap; j += 4) {
        int nb = j + grp;
        bool v = nb < dcap;
        int s = __shfl(ids, v ? nb : 0);
        uint2 u = *(const uint2*)(feat + s * 64 + fb);
        if (v) {
            s0 += bflo(u.x);
            s1 += bfhi(u.x);
            s2 += bflo(u.y);
            s3 += bfhi(u.y);
        }
    }
    // reduce across the 4 subgroups (lanes ^16, ^32)
    s0 += __shfl_xor(s0, 16); s0 += __shfl_xor(s0, 32);
    s1 += __shfl_xor(s1, 16); s1 += __shfl_xor(s1, 32);
    s2 += __shfl_xor(s2, 16); s2 += __shfl_xor(s2, 32);
    s3 += __shfl_xor(s3, 16); s3 += __shfl_xor(s3, 32);
    if (l < 16) {
        float inv = 1.0f / fmaxf((float)deg, 1.0f);
        *(float4*)&agg[wid * 64 + fb] =
            make_float4(s0 * inv, s1 * inv, s2 * inv, s3 * inv);
    }
}

// Layer-1 overflow: add x*inv into mean (fp32 x; overflow is ~never hit).
__global__ __launch_bounds__(64) void ovf_scatter_kernel(
        const float* __restrict__ feat, const int* __restrict__ ovf,
        const int* __restrict__ ovfc, const int* __restrict__ counts,
        float* __restrict__ agg) {
    int n = *ovfc;
    if (n > OVF_CAP) n = OVF_CAP;
    for (int idx = blockIdx.x; idx < n; idx += gridDim.x) {
        int s = ovf[idx * 2];
        int d = ovf[idx * 2 + 1];
        float inv = 1.0f / fmaxf((float)counts[d], 1.0f);
        atomicAdd(&agg[d * 64 + threadIdx.x], feat[s * 64 + threadIdx.x] * inv);
    }
}

// Layer 1 MFMA, B-stationary: h = relu( [mean|x] @ [W1l;W1r] + b1 )
__global__ __launch_bounds__(256) void l1_mfma_kernel(
        const float* __restrict__ mean1, const float* __restrict__ x,
        const short* __restrict__ Bf1, const float* __restrict__ b1,
        float* __restrict__ h) {
    const int w = threadIdx.x >> 6;
    const int l = threadIdx.x & 63;
    const int lane15 = l & 15;
    const int quad = l >> 4;
    const int rowBase = blockIdx.x * 128;

    bf16x8 bh[2][4], bl[2][4];
#pragma unroll
    for (int ci = 0; ci < 2; ++ci) {
        const int c = 2 * w + ci;
#pragma unroll
        for (int kc = 0; kc < 4; ++kc) {
            const short* bp = Bf1 + ((c * 4 + kc) * 2) * 512 + l * 8;
            bh[ci][kc] = *(const bf16x8*)bp;
            bl[ci][kc] = *(const bf16x8*)(bp + 512);
        }
    }
    float bias[2];
#pragma unroll
    for (int ci = 0; ci < 2; ++ci) bias[ci] = b1[(2 * w + ci) * 16 + lane15];

#pragma unroll
    for (int rt = 0; rt < 8; ++rt) {
        const int row = rowBase + rt * 16 + lane15;
        const bool rv = row < N_NODES;

        bf16x8 ah[4], al[4];
#pragma unroll
        for (int kc = 0; kc < 4; ++kc) {
            float4 v0 = make_float4(0.f, 0.f, 0.f, 0.f);
            float4 v1 = make_float4(0.f, 0.f, 0.f, 0.f);
            if (rv) {
                const float* src = (kc < 2)
                    ? (mean1 + row * 64 + kc * 32 + quad * 8)
                    : (x     + row * 64 + (kc - 2) * 32 + quad * 8);
                v0 = *(const float4*)src;
                v1 = *(const float4*)(src + 4);
            }
            float f[8] = {v0.x, v0.y, v0.z, v0.w, v1.x, v1.y, v1.z, v1.w};
#pragma unroll
            for (int j = 0; j < 8; ++j) {
                unsigned u = __float_as_uint(f[j]);
                unsigned hb = u >> 16;
                float fh = __uint_as_float(hb << 16);
                unsigned lb = __float_as_uint(f[j] - fh) >> 16;
                ah[kc][j] = (short)hb;
                al[kc][j] = (short)lb;
            }
        }

        f32x4 acc[2] = {(f32x4){0.f, 0.f, 0.f, 0.f}, (f32x4){0.f, 0.f, 0.f, 0.f}};
#pragma unroll
        for (int kc = 0; kc < 4; ++kc) {
#pragma unroll
            for (int ci = 0; ci < 2; ++ci) {
                acc[ci] = __builtin_amdgcn_mfma_f32_16x16x32_bf16(ah[kc], bh[ci][kc], acc[ci], 0, 0, 0);
                acc[ci] = __builtin_amdgcn_mfma_f32_16x16x32_bf16(al[kc], bh[ci][kc], acc[ci], 0, 0, 0);
                acc[ci] = __builtin_amdgcn_mfma_f32_16x16x32_bf16(ah[kc], bl[ci][kc], acc[ci], 0, 0, 0);
            }
        }

        const int rb = rowBase + rt * 16 + quad * 4;
#pragma unroll
        for (int ci = 0; ci < 2; ++ci) {
            const int col = (2 * w + ci) * 16 + lane15;
#pragma unroll
            for (int i = 0; i < 4; ++i) {
                int r = rb + i;
                if (r < N_NODES)
                    h[r * 128 + col] = fmaxf(acc[ci][i] + bias[ci], 0.f);
            }
        }
    }
}

// Layer 2 MFMA, B-stationary: p(bf16) = h @ W2l ; q(fp32) = h @ W2r + b2
__global__ __launch_bounds__(256) void l2_mfma_kernel(
        const float* __restrict__ h, const short* __restrict__ Bf2,
        const float* __restrict__ b2,
        unsigned short* __restrict__ p_bf, float* __restrict__ q) {
    const int w = threadIdx.x >> 6;
    const int l = threadIdx.x & 63;
    const int lane15 = l & 15;
    const int quad = l >> 4;
    const int rowBase = blockIdx.x * 128;

    bf16x8 bh[2][4], bl[2][4];
#pragma unroll
    for (int ci = 0; ci < 2; ++ci) {
        const int c = 2 * w + ci;
#pragma unroll
        for (int kc = 0; kc < 4; ++kc) {
            const short* bp = Bf2 + ((c * 4 + kc) * 2) * 512 + l * 8;
            bh[ci][kc] = *(const bf16x8*)bp;
            bl[ci][kc] = *(const bf16x8*)(bp + 512);
        }
    }
    float bias[2];
#pragma unroll
    for (int ci = 0; ci < 2; ++ci) {
        const int c = 2 * w + ci;
        bias[ci] = (c >= 4) ? b2[(c - 4) * 16 + lane15] : 0.f;
    }

#pragma unroll
    for (int rt = 0; rt < 8; ++rt) {
        const int row = rowBase + rt * 16 + lane15;
        const bool rv = row < N_NODES;

        bf16x8 ah[4], al[4];
#pragma unroll
        for (int kc = 0; kc < 4; ++kc) {
            float4 v0 = make_float4(0.f, 0.f, 0.f, 0.f);
            float4 v1 = make_float4(0.f, 0.f, 0.f, 0.f);
            if (rv) {
                const float* src = h + row * 128 + kc * 32 + quad * 8;
                v0 = *(const float4*)src;
                v1 = *(const float4*)(src + 4);
            }
            float f[8] = {v0.x, v0.y, v0.z, v0.w, v1.x, v1.y, v1.z, v1.w};
#pragma unroll
            for (int j = 0; j < 8; ++j) {
                unsigned u = __float_as_uint(f[j]);
                unsigned hb = u >> 16;
                float fh = __uint_as_float(hb << 16);
                unsigned lb = __float_as_uint(f[j] - fh) >> 16;
                ah[kc][j] = (short)hb;
                al[kc][j] = (short)lb;
            }
        }

        f32x4 acc[2] = {(f32x4){0.f, 0.f, 0.f, 0.f}, (f32x4){0.f, 0.f, 0.f, 0.f}};
#pragma unroll
        for (int kc = 0; kc < 4; ++kc) {
#pragma unroll
            for (int ci = 0; ci < 2; ++ci) {
                acc[ci] = __builtin_amdgcn_mfma_f32_16x16x32_bf16(ah[kc], bh[ci][kc], acc[ci], 0, 0, 0);
                acc[ci] = __builtin_amdgcn_mfma_f32_16x16x32_bf16(al[kc], bh[ci][kc], acc[ci], 0, 0, 0);
                acc[ci] = __builtin_amdgcn_mfma_f32_16x16x32_bf16(ah[kc], bl[ci][kc], acc[ci], 0, 0, 0);
            }
        }

        const int rb = rowBase + rt * 16 + quad * 4;
#pragma unroll
        for (int ci = 0; ci < 2; ++ci) {
            const int c = 2 * w + ci;
            if (c < 4) {
#pragma unroll
                for (int i = 0; i < 4; ++i) {
                    int r = rb + i;
                    if (r < N_NODES)
                        p_bf[r * 64 + c * 16 + lane15] = f2bf(acc[ci][i]);
                }
            } else {
#pragma unroll
                for (int i = 0; i < 4; ++i) {
                    int r = rb + i;
                    if (r < N_NODES)
                        q[r * 64 + (c - 4) * 16 + lane15] = acc[ci][i] + bias[ci];
                }
            }
        }
    }
}

// Fused layer-2 aggregation + epilogue: out = mean(p_bf[nbrs]) + q
__global__ __launch_bounds__(256) void gather_final_kernel(
        const unsigned short* __restrict__ p, const int* __restrict__ counts,
        const int* __restrict__ nodeBase, const int* __restrict__ csr,
        const float* __restrict__ q, float* __restrict__ out) {
    int wid = blockIdx.x * 4 + (threadIdx.x >> 6);
    int l = threadIdx.x & 63;
    if (wid >= N_NODES) return;
    int deg = counts[wid];
    int dcap = min(deg, DEG_CAP);
    int base = nodeBase[wid];
    int ids = (l < dcap) ? csr[base + l] : 0;
    const int grp = l >> 4;
    const int fb = (l & 15) * 4;
    float s0 = 0.f, s1 = 0.f, s2 = 0.f, s3 = 0.f;
    int j = 0;
    for (; j + 8 <= dcap; j += 8) {
        int sA = __shfl(ids, j + grp);
        int sB = __shfl(ids, j + 4 + grp);
        uint2 uA = *(const uint2*)(p + sA * 64 + fb);
        uint2 uB = *(const uint2*)(p + sB * 64 + fb);
        s0 += bflo(uA.x) + bflo(uB.x);
        s1 += bfhi(uA.x) + bfhi(uB.x);
        s2 += bflo(uA.y) + bflo(uB.y);
        s3 += bfhi(uA.y) + bfhi(uB.y);
    }
    for (; j < dcap; j += 4) {
        int nb = j + grp;
        bool v = nb < dcap;
        int s = __shfl(ids, v ? nb : 0);
        uint2 u = *(const uint2*)(p + s * 64 + fb);
        if (v) {
            s0 += bflo(u.x);
            s1 += bfhi(u.x);
            s2 += bflo(u.y);
            s3 += bfhi(u.y);
        }
    }
    s0 += __shfl_xor(s0, 16); s0 += __shfl_xor(s0, 32);
    s1 += __shfl_xor(s1, 16); s1 += __shfl_xor(s1, 32);
    s2 += __shfl_xor(s2, 16); s2 += __shfl_xor(s2, 32);
    s3 += __shfl_xor(s3, 16); s3 += __shfl_xor(s3, 32);
    if (l < 16) {
        float inv = 1.0f / fmaxf((float)deg, 1.0f);
        float4 qv = *(const float4*)&q[wid * 64 + fb];
        *(float4*)&out[wid * 64 + fb] =
            make_float4(s0 * inv + qv.x, s1 * inv + qv.y,
                        s2 * inv + qv.z, s3 * inv + qv.w);
    }
}

// Layer-2 overflow fix-up (additive).
__global__ __launch_bounds__(64) void ovf_fixup_kernel(
        const unsigned short* __restrict__ p, const int* __restrict__ ovf,
        const int* __restrict__ ovfc, const int* __restrict__ counts,
        float* __restrict__ out) {
    int n = *ovfc;
    if (n > OVF_CAP) n = OVF_CAP;
    for (int idx = blockIdx.x; idx < n; idx += gridDim.x) {
        int s = ovf[idx * 2];
        int d = ovf[idx * 2 + 1];
        float inv = 1.0f / fmaxf((float)counts[d], 1.0f);
        atomicAdd(&out[d * 64 + threadIdx.x],
                  bf2f(p[s * 64 + threadIdx.x]) * inv);
    }
}

extern "C" void kernel_launch(void* const* d_in, const int* in_sizes, int n_in,
                              void* d_out, int out_size, void* d_ws, size_t ws_size,
                              hipStream_t stream) {
    const float* x   = (const float*)d_in[0];
    const float* W1l = (const float*)d_in[1];
    const float* W1r = (const float*)d_in[2];
    const float* b1  = (const float*)d_in[3];
    const float* W2l = (const float*)d_in[4];
    const float* W2r = (const float*)d_in[5];
    const float* b2  = (const float*)d_in[6];
    const int*   ei  = (const int*)d_in[7];

    int*   wsi      = (int*)d_ws;
    float* wsf      = (float*)d_ws;
    int*   counts_r = wsi;
    int*   prefs_r  = wsi + 802816;
    int*   counts   = wsi + 1605632;
    unsigned short* pos16 = (unsigned short*)(wsi + 1705984);
    int*   ovfc     = wsi + 2205984;
    int*   cursor   = wsi + 2205985;
    int*   ovf      = wsi + 2206048;
    short* Bf1      = (short*)(wsi + 2214240);
    short* Bf2      = (short*)(wsi + 2230624);
    int*   nodeBase = wsi + 2247008;
    int*   csr      = wsi + 2347008;
    unsigned short* xb = (unsigned short*)(wsi + 8647008);
    float* mean1    = wsf + 11847008;
    unsigned short* p_bf = (unsigned short*)(wsf + 11847008);  // reuse after l1
    float* h        = wsf + 18247008;
    float* q        = wsf + 31047008;
    float* out      = (float*)d_out;

    prep_kernel<<<(N_NODES * 16 + 255) / 256, 256, 0, stream>>>(
        (const float4*)x, (ushort4*)xb, W1l, W1r, W2l, W2r, Bf1, Bf2,
        (int4*)counts_r, ovfc, cursor);
    hist_kernel<<<(N_EDGES + 255) / 256, 256, 0, stream>>>(ei, counts_r, pos16);
    scan_kernel<<<(N_NODES + 255) / 256, 256, 0, stream>>>(
        counts_r, prefs_r, counts, nodeBase, cursor);
    fill_kernel<<<(N_EDGES + 255) / 256, 256, 0, stream>>>(
        ei, pos16, prefs_r, nodeBase, csr, ovfc, ovf);

    gather_bf_kernel<<<(N_NODES + 3) / 4, 256, 0, stream>>>(
        xb, counts, nodeBase, csr, mean1);
    ovf_scatter_kernel<<<64, 64, 0, stream>>>(x, ovf, ovfc, counts, mean1);

    l1_mfma_kernel<<<(N_NODES + 127) / 128, 256, 0, stream>>>(
        mean1, x, Bf1, b1, h);
    l2_mfma_kernel<<<(N_NODES + 127) / 128, 256, 0, stream>>>(h, Bf2, b2, p_bf, q);

    gather_final_kernel<<<(N_NODES + 3) / 4, 256, 0, stream>>>(
        p_bf, counts, nodeBase, csr, q, out);
    ovf_fixup_kernel<<<64, 64, 0, stream>>>(p_bf, ovf, ovfc, counts, out);
}

// Round 2
// 295.072 us; speedup vs baseline: 1.0728x; 1.0728x over previous
//
#include <hip/hip_runtime.h>

#define N_NODES 100000
#define N_EDGES 1000000
#define DEG_CAP 64
#define OVF_CAP 4096

typedef __attribute__((ext_vector_type(8))) short bf16x8;
typedef __attribute__((ext_vector_type(4))) float f32x4;

__device__ __forceinline__ unsigned short f2bf(float f) {
    unsigned u = __float_as_uint(f);
    return (unsigned short)((u + 0x7FFF + ((u >> 16) & 1)) >> 16);
}
__device__ __forceinline__ float bf2f(unsigned short b) {
    return __uint_as_float(((unsigned)b) << 16);
}
__device__ __forceinline__ float bflo(unsigned u) {   // low bf16 of a dword
    return __uint_as_float(u << 16);
}
__device__ __forceinline__ float bfhi(unsigned u) {   // high bf16 of a dword
    return __uint_as_float(u & 0xffff0000u);
}

// ws layout (4B units):
//   counts   : int [0,      100352)
//   ovfc     : int [100352]
//   ovf      : int [100416, 108608)
//   Bf1      : s16 [108608, 124992)    32768 halfs (frag-ordered hi/lo)
//   Bf2      : s16 [124992, 141376)
//   slots    : int [141376, 6541376)   N*64 padded
//   xb       : u16 [6541376, 9741376)  N*64 bf16
//   mean1    : f32 [9741376, 16141376) N*64; reused as p_bf after l1
//   h        : f32 [16141376, 28941376) N*128
//   q        : f32 [28941376, 35341376) N*64
// total 35,341,376 * 4B = 141.4 MB

// Merged init + weight-split + x->bf16 (one launch).
__global__ __launch_bounds__(256) void prep_kernel(
        const float4* __restrict__ x4, ushort4* __restrict__ xb4,
        const float* __restrict__ W1l, const float* __restrict__ W1r,
        const float* __restrict__ W2l, const float* __restrict__ W2r,
        short* __restrict__ Bf1, short* __restrict__ Bf2,
        int4* __restrict__ counts4, int* __restrict__ ovfc) {
    int i = blockIdx.x * blockDim.x + threadIdx.x;
    if (i < 100352 / 4) counts4[i] = make_int4(0, 0, 0, 0);
    if (i == 0) *ovfc = 0;
    if (i < 32768) {
        int g = i >> 14;
        int e = i & 16383;
        int k = e >> 7;
        int n = e & 127;
        float v;
        if (g == 0) v = (k < 64) ? W1l[k * 128 + n] : W1r[(k - 64) * 128 + n];
        else        v = (n < 64) ? W2l[k * 64 + n]  : W2r[k * 64 + (n - 64)];
        unsigned u = __float_as_uint(v);
        unsigned hb = u >> 16;
        float vh = __uint_as_float(hb << 16);
        unsigned lb = __float_as_uint(v - vh) >> 16;
        int c = n >> 4, kc = k >> 5;
        int lane = (((k >> 3) & 3) << 4) | (n & 15);
        int j = k & 7;
        short* base = g ? Bf2 : Bf1;
        base[((c * 4 + kc) * 2 + 0) * 512 + lane * 8 + j] = (short)hb;
        base[((c * 4 + kc) * 2 + 1) * 512 + lane * 8 + j] = (short)lb;
    }
    if (i < N_NODES * 16) {
        float4 v = x4[i];
        ushort4 o;
        o.x = f2bf(v.x); o.y = f2bf(v.y); o.z = f2bf(v.z); o.w = f2bf(v.w);
        xb4[i] = o;
    }
}

// Merged histogram + slot fill: ONE global atomic per edge (the atomic
// pass is irreducible — global atomics execute at the memory-side RMW
// point at ~10/cycle chip-wide regardless of scope; measured identical
// WRITE_SIZE/duration with workgroup vs agent scope). The fetch_add
// result IS the slot position, so the separate scan/fill passes (one
// full extra edge pass + pos16 round trip) are deleted. Slot scatter
// overlaps under the atomic latency.
__global__ __launch_bounds__(256) void histfill_kernel(
        const int* __restrict__ ei, int* __restrict__ counts,
        int* __restrict__ slots, int* __restrict__ ovfc,
        int* __restrict__ ovf) {
    int e = blockIdx.x * blockDim.x + threadIdx.x;
    if (e >= N_EDGES) return;
    int s = ei[e];
    int d = ei[N_EDGES + e];
    int pos = atomicAdd(&counts[d], 1);
    if (pos < DEG_CAP) {
        slots[d * DEG_CAP + pos] = s;
    } else {
        int o = atomicAdd(ovfc, 1);
        if (o < OVF_CAP) { ovf[o * 2] = s; ovf[o * 2 + 1] = d; }
    }
}

// One wave per node. Lane l: neighbor subgroup l>>4, features (l&15)*4..+3.
// One dwordx2 load covers 4 bf16 features of one neighbor; 4 subgroups ->
// 4 neighbor rows per load instruction. Butterfly-reduce across subgroups.
// Writes the MEAN (fp32).
__global__ __launch_bounds__(256) void gather_bf_kernel(
        const unsigned short* __restrict__ feat, const int* __restrict__ counts,
        const int* __restrict__ slots, float* __restrict__ agg) {
    int wid = blockIdx.x * 4 + (threadIdx.x >> 6);
    int l = threadIdx.x & 63;
    if (wid >= N_NODES) return;
    int deg = counts[wid];
    int dcap = min(deg, DEG_CAP);
    int ids = slots[wid * DEG_CAP + l];
    const int grp = l >> 4;
    const int fb = (l & 15) * 4;
    float s0 = 0.f, s1 = 0.f, s2 = 0.f, s3 = 0.f;
    int j = 0;
    for (; j + 8 <= dcap; j += 8) {   // grp<=3 -> both neighbors in-range
        int sA = __shfl(ids, j + grp);
        int sB = __shfl(ids, j + 4 + grp);
        uint2 uA = *(const uint2*)(feat + sA * 64 + fb);
        uint2 uB = *(const uint2*)(feat + sB * 64 + fb);
        s0 += bflo(uA.x) + bflo(uB.x);
        s1 += bfhi(uA.x) + bfhi(uB.x);
        s2 += bflo(uA.y) + bflo(uB.y);
        s3 += bfhi(uA.y) + bfhi(uB.y);
    }
    for (; j < dcap; j += 4) {
        int nb = j + grp;
        bool v = nb < dcap;
        int s = __shfl(ids, v ? nb : 0);
        uint2 u = *(const uint2*)(feat + s * 64 + fb);
        if (v) {
            s0 += bflo(u.x);
            s1 += bfhi(u.x);
            s2 += bflo(u.y);
            s3 += bfhi(u.y);
        }
    }
    // reduce across the 4 subgroups (lanes ^16, ^32)
    s0 += __shfl_xor(s0, 16); s0 += __shfl_xor(s0, 32);
    s1 += __shfl_xor(s1, 16); s1 += __shfl_xor(s1, 32);
    s2 += __shfl_xor(s2, 16); s2 += __shfl_xor(s2, 32);
    s3 += __shfl_xor(s3, 16); s3 += __shfl_xor(s3, 32);
    if (l < 16) {
        float inv = 1.0f / fmaxf((float)deg, 1.0f);
        *(float4*)&agg[wid * 64 + fb] =
            make_float4(s0 * inv, s1 * inv, s2 * inv, s3 * inv);
    }
}

// Layer-1 overflow: add x*inv into mean (fp32 x; overflow is ~never hit).
__global__ __launch_bounds__(64) void ovf_scatter_kernel(
        const float* __restrict__ feat, const int* __restrict__ ovf,
        const int* __restrict__ ovfc, const int* __restrict__ counts,
        float* __restrict__ agg) {
    int n = *ovfc;
    if (n > OVF_CAP) n = OVF_CAP;
    for (int idx = blockIdx.x; idx < n; idx += gridDim.x) {
        int s = ovf[idx * 2];
        int d = ovf[idx * 2 + 1];
        float inv = 1.0f / fmaxf((float)counts[d], 1.0f);
        atomicAdd(&agg[d * 64 + threadIdx.x], feat[s * 64 + threadIdx.x] * inv);
    }
}

// Layer 1 MFMA, B-stationary: h = relu( [mean|x] @ [W1l;W1r] + b1 )
// Block = 128 rows. Wave w owns col-tiles {2w, 2w+1}; its 16 B-frags (64
// VGPR) are loaded from L2 ONCE, then 8 row-tiles of A stream against them.
__global__ __launch_bounds__(256) void l1_mfma_kernel(
        const float* __restrict__ mean1, const float* __restrict__ x,
        const short* __restrict__ Bf1, const float* __restrict__ b1,
        float* __restrict__ h) {
    const int w = threadIdx.x >> 6;
    const int l = threadIdx.x & 63;
    const int lane15 = l & 15;
    const int quad = l >> 4;
    const int rowBase = blockIdx.x * 128;

    bf16x8 bh[2][4], bl[2][4];
#pragma unroll
    for (int ci = 0; ci < 2; ++ci) {
        const int c = 2 * w + ci;
#pragma unroll
        for (int kc = 0; kc < 4; ++kc) {
            const short* bp = Bf1 + ((c * 4 + kc) * 2) * 512 + l * 8;
            bh[ci][kc] = *(const bf16x8*)bp;
            bl[ci][kc] = *(const bf16x8*)(bp + 512);
        }
    }
    float bias[2];
#pragma unroll
    for (int ci = 0; ci < 2; ++ci) bias[ci] = b1[(2 * w + ci) * 16 + lane15];

#pragma unroll
    for (int rt = 0; rt < 8; ++rt) {
        const int row = rowBase + rt * 16 + lane15;
        const bool rv = row < N_NODES;

        bf16x8 ah[4], al[4];
#pragma unroll
        for (int kc = 0; kc < 4; ++kc) {
            float4 v0 = make_float4(0.f, 0.f, 0.f, 0.f);
            float4 v1 = make_float4(0.f, 0.f, 0.f, 0.f);
            if (rv) {
                const float* src = (kc < 2)
                    ? (mean1 + row * 64 + kc * 32 + quad * 8)
                    : (x     + row * 64 + (kc - 2) * 32 + quad * 8);
                v0 = *(const float4*)src;
                v1 = *(const float4*)(src + 4);
            }
            float f[8] = {v0.x, v0.y, v0.z, v0.w, v1.x, v1.y, v1.z, v1.w};
#pragma unroll
            for (int j = 0; j < 8; ++j) {
                unsigned u = __float_as_uint(f[j]);
                unsigned hb = u >> 16;
                float fh = __uint_as_float(hb << 16);
                unsigned lb = __float_as_uint(f[j] - fh) >> 16;
                ah[kc][j] = (short)hb;
                al[kc][j] = (short)lb;
            }
        }

        f32x4 acc[2] = {(f32x4){0.f, 0.f, 0.f, 0.f}, (f32x4){0.f, 0.f, 0.f, 0.f}};
#pragma unroll
        for (int kc = 0; kc < 4; ++kc) {
#pragma unroll
            for (int ci = 0; ci < 2; ++ci) {
                acc[ci] = __builtin_amdgcn_mfma_f32_16x16x32_bf16(ah[kc], bh[ci][kc], acc[ci], 0, 0, 0);
                acc[ci] = __builtin_amdgcn_mfma_f32_16x16x32_bf16(al[kc], bh[ci][kc], acc[ci], 0, 0, 0);
                acc[ci] = __builtin_amdgcn_mfma_f32_16x16x32_bf16(ah[kc], bl[ci][kc], acc[ci], 0, 0, 0);
            }
        }

        // C layout: col = c*16 + lane15, row = quad*4 + i
        const int rb = rowBase + rt * 16 + quad * 4;
#pragma unroll
        for (int ci = 0; ci < 2; ++ci) {
            const int col = (2 * w + ci) * 16 + lane15;
#pragma unroll
            for (int i = 0; i < 4; ++i) {
                int r = rb + i;
                if (r < N_NODES)
                    h[r * 128 + col] = fmaxf(acc[ci][i] + bias[ci], 0.f);
            }
        }
    }
}

// Layer 2 MFMA, B-stationary: p(bf16) = h @ W2l ; q(fp32) = h @ W2r + b2
// Waves 0-1 own c=0..3 (p half), waves 2-3 own c=4..7 (q half).
__global__ __launch_bounds__(256) void l2_mfma_kernel(
        const float* __restrict__ h, const short* __restrict__ Bf2,
        const float* __restrict__ b2,
        unsigned short* __restrict__ p_bf, float* __restrict__ q) {
    const int w = threadIdx.x >> 6;
    const int l = threadIdx.x & 63;
    const int lane15 = l & 15;
    const int quad = l >> 4;
    const int rowBase = blockIdx.x * 128;

    bf16x8 bh[2][4], bl[2][4];
#pragma unroll
    for (int ci = 0; ci < 2; ++ci) {
        const int c = 2 * w + ci;
#pragma unroll
        for (int kc = 0; kc < 4; ++kc) {
            const short* bp = Bf2 + ((c * 4 + kc) * 2) * 512 + l * 8;
            bh[ci][kc] = *(const bf16x8*)bp;
            bl[ci][kc] = *(const bf16x8*)(bp + 512);
        }
    }
    float bias[2];
#pragma unroll
    for (int ci = 0; ci < 2; ++ci) {
        const int c = 2 * w + ci;
        bias[ci] = (c >= 4) ? b2[(c - 4) * 16 + lane15] : 0.f;
    }

#pragma unroll
    for (int rt = 0; rt < 8; ++rt) {
        const int row = rowBase + rt * 16 + lane15;
        const bool rv = row < N_NODES;

        bf16x8 ah[4], al[4];
#pragma unroll
        for (int kc = 0; kc < 4; ++kc) {
            float4 v0 = make_float4(0.f, 0.f, 0.f, 0.f);
            float4 v1 = make_float4(0.f, 0.f, 0.f, 0.f);
            if (rv) {
                const float* src = h + row * 128 + kc * 32 + quad * 8;
                v0 = *(const float4*)src;
                v1 = *(const float4*)(src + 4);
            }
            float f[8] = {v0.x, v0.y, v0.z, v0.w, v1.x, v1.y, v1.z, v1.w};
#pragma unroll
            for (int j = 0; j < 8; ++j) {
                unsigned u = __float_as_uint(f[j]);
                unsigned hb = u >> 16;
                float fh = __uint_as_float(hb << 16);
                unsigned lb = __float_as_uint(f[j] - fh) >> 16;
                ah[kc][j] = (short)hb;
                al[kc][j] = (short)lb;
            }
        }

        f32x4 acc[2] = {(f32x4){0.f, 0.f, 0.f, 0.f}, (f32x4){0.f, 0.f, 0.f, 0.f}};
#pragma unroll
        for (int kc = 0; kc < 4; ++kc) {
#pragma unroll
            for (int ci = 0; ci < 2; ++ci) {
                acc[ci] = __builtin_amdgcn_mfma_f32_16x16x32_bf16(ah[kc], bh[ci][kc], acc[ci], 0, 0, 0);
                acc[ci] = __builtin_amdgcn_mfma_f32_16x16x32_bf16(al[kc], bh[ci][kc], acc[ci], 0, 0, 0);
                acc[ci] = __builtin_amdgcn_mfma_f32_16x16x32_bf16(ah[kc], bl[ci][kc], acc[ci], 0, 0, 0);
            }
        }

        const int rb = rowBase + rt * 16 + quad * 4;
#pragma unroll
        for (int ci = 0; ci < 2; ++ci) {
            const int c = 2 * w + ci;
            if (c < 4) {
#pragma unroll
                for (int i = 0; i < 4; ++i) {
                    int r = rb + i;
                    if (r < N_NODES)
                        p_bf[r * 64 + c * 16 + lane15] = f2bf(acc[ci][i]);
                }
            } else {
#pragma unroll
                for (int i = 0; i < 4; ++i) {
                    int r = rb + i;
                    if (r < N_NODES)
                        q[r * 64 + (c - 4) * 16 + lane15] = acc[ci][i] + bias[ci];
                }
            }
        }
    }
}

// Fused layer-2 aggregation + epilogue: out = mean(p_bf[nbrs]) + q
// Same 4-neighbors-per-load structure as gather_bf_kernel.
__global__ __launch_bounds__(256) void gather_final_kernel(
        const unsigned short* __restrict__ p, const int* __restrict__ counts,
        const int* __restrict__ slots, const float* __restrict__ q,
        float* __restrict__ out) {
    int wid = blockIdx.x * 4 + (threadIdx.x >> 6);
    int l = threadIdx.x & 63;
    if (wid >= N_NODES) return;
    int deg = counts[wid];
    int dcap = min(deg, DEG_CAP);
    int ids = slots[wid * DEG_CAP + l];
    const int grp = l >> 4;
    const int fb = (l & 15) * 4;
    float s0 = 0.f, s1 = 0.f, s2 = 0.f, s3 = 0.f;
    int j = 0;
    for (; j + 8 <= dcap; j += 8) {
        int sA = __shfl(ids, j + grp);
        int sB = __shfl(ids, j + 4 + grp);
        uint2 uA = *(const uint2*)(p + sA * 64 + fb);
        uint2 uB = *(const uint2*)(p + sB * 64 + fb);
        s0 += bflo(uA.x) + bflo(uB.x);
        s1 += bfhi(uA.x) + bfhi(uB.x);
        s2 += bflo(uA.y) + bflo(uB.y);
        s3 += bfhi(uA.y) + bfhi(uB.y);
    }
    for (; j < dcap; j += 4) {
        int nb = j + grp;
        bool v = nb < dcap;
        int s = __shfl(ids, v ? nb : 0);
        uint2 u = *(const uint2*)(p + s * 64 + fb);
        if (v) {
            s0 += bflo(u.x);
            s1 += bfhi(u.x);
            s2 += bflo(u.y);
            s3 += bfhi(u.y);
        }
    }
    s0 += __shfl_xor(s0, 16); s0 += __shfl_xor(s0, 32);
    s1 += __shfl_xor(s1, 16); s1 += __shfl_xor(s1, 32);
    s2 += __shfl_xor(s2, 16); s2 += __shfl_xor(s2, 32);
    s3 += __shfl_xor(s3, 16); s3 += __shfl_xor(s3, 32);
    if (l < 16) {
        float inv = 1.0f / fmaxf((float)deg, 1.0f);
        float4 qv = *(const float4*)&q[wid * 64 + fb];
        *(float4*)&out[wid * 64 + fb] =
            make_float4(s0 * inv + qv.x, s1 * inv + qv.y,
                        s2 * inv + qv.z, s3 * inv + qv.w);
    }
}

// Layer-2 overflow fix-up (additive).
__global__ __launch_bounds__(64) void ovf_fixup_kernel(
        const unsigned short* __restrict__ p, const int* __restrict__ ovf,
        const int* __restrict__ ovfc, const int* __restrict__ counts,
        float* __restrict__ out) {
    int n = *ovfc;
    if (n > OVF_CAP) n = OVF_CAP;
    for (int idx = blockIdx.x; idx < n; idx += gridDim.x) {
        int s = ovf[idx * 2];
        int d = ovf[idx * 2 + 1];
        float inv = 1.0f / fmaxf((float)counts[d], 1.0f);
        atomicAdd(&out[d * 64 + threadIdx.x],
                  bf2f(p[s * 64 + threadIdx.x]) * inv);
    }
}

extern "C" void kernel_launch(void* const* d_in, const int* in_sizes, int n_in,
                              void* d_out, int out_size, void* d_ws, size_t ws_size,
                              hipStream_t stream) {
    const float* x   = (const float*)d_in[0];
    const float* W1l = (const float*)d_in[1];
    const float* W1r = (const float*)d_in[2];
    const float* b1  = (const float*)d_in[3];
    const float* W2l = (const float*)d_in[4];
    const float* W2r = (const float*)d_in[5];
    const float* b2  = (const float*)d_in[6];
    const int*   ei  = (const int*)d_in[7];

    int*   wsi      = (int*)d_ws;
    float* wsf      = (float*)d_ws;
    int*   counts   = wsi;
    int*   ovfc     = wsi + 100352;
    int*   ovf      = wsi + 100416;
    short* Bf1      = (short*)(wsi + 108608);
    short* Bf2      = (short*)(wsi + 124992);
    int*   slots    = wsi + 141376;
    unsigned short* xb = (unsigned short*)(wsi + 6541376);
    float* mean1    = wsf + 9741376;
    unsigned short* p_bf = (unsigned short*)(wsf + 9741376);  // reuse after l1
    float* h        = wsf + 16141376;
    float* q        = wsf + 28941376;
    float* out      = (float*)d_out;

    // merged init + prep (covers max(25088, 32768, 1.6M) indices)
    prep_kernel<<<(N_NODES * 16 + 255) / 256, 256, 0, stream>>>(
        (const float4*)x, (ushort4*)xb, W1l, W1r, W2l, W2r, Bf1, Bf2,
        (int4*)counts, ovfc);
    // single atomic pass: count + direct slot fill
    histfill_kernel<<<(N_EDGES + 255) / 256, 256, 0, stream>>>(
        ei, counts, slots, ovfc, ovf);

    // layer-1 aggregation -> mean (bf16 rows), + overflow
    gather_bf_kernel<<<(N_NODES + 3) / 4, 256, 0, stream>>>(xb, counts, slots, mean1);
    ovf_scatter_kernel<<<64, 64, 0, stream>>>(x, ovf, ovfc, counts, mean1);

    // h = relu([mean|x] @ [W1l;W1r] + b1)
    l1_mfma_kernel<<<(N_NODES + 127) / 128, 256, 0, stream>>>(
        mean1, x, Bf1, b1, h);
    // p(bf16) = h @ W2l ; q = h @ W2r + b2   (p_bf overwrites mean1)
    l2_mfma_kernel<<<(N_NODES + 127) / 128, 256, 0, stream>>>(h, Bf2, b2, p_bf, q);

    // fused layer-2 aggregation + epilogue, then overflow fix-up
    gather_final_kernel<<<(N_NODES + 3) / 4, 256, 0, stream>>>(
        p_bf, counts, slots, q, out);
    ovf_fixup_kernel<<<64, 64, 0, stream>>>(p_bf, ovf, ovfc, counts, out);
}

// Round 4
// 255.699 us; speedup vs baseline: 1.2380x; 1.1540x over previous
//
#include <hip/hip_runtime.h>

#define N_NODES 100000
#define N_EDGES 1000000
#define DEG_CAP 64
#define OVF_CAP 4096
#define SPILL_CAP 4096

// binning geometry
#define BKT_SH 8
#define BKT_NODES 256            // nodes per bucket
#define NBKT 392                 // 392*256 = 100352 >= N_NODES
#define BKT_CAP 4096             // record capacity per bucket (mean ~2551, 31 sigma)
#define BIN_CHUNK 4096           // edges per bin block
#define FIFO_CAP 32              // LDS fifo depth per bucket (mean ~10.4)

typedef __attribute__((ext_vector_type(8))) short bf16x8;
typedef __attribute__((ext_vector_type(4))) float f32x4;

__device__ __forceinline__ unsigned short f2bf(float f) {
    unsigned u = __float_as_uint(f);
    return (unsigned short)((u + 0x7FFF + ((u >> 16) & 1)) >> 16);
}
__device__ __forceinline__ float bf2f(unsigned short b) {
    return __uint_as_float(((unsigned)b) << 16);
}
__device__ __forceinline__ float bflo(unsigned u) {   // low bf16 of a dword
    return __uint_as_float(u << 16);
}
__device__ __forceinline__ float bfhi(unsigned u) {   // high bf16 of a dword
    return __uint_as_float(u & 0xffff0000u);
}

// ws layout (4B units) — AUDITED SIZES:
//   counts   : int [0, 100352)
//   ovfc     : 100352 ; spillc : 100353
//   gcur     : [100416, 100928)           512 ints (392 used)
//   ovf      : [100928, 109120)           2*4096
//   spill    : [109120, 117312)           4096 int2
//   Bf1      : s16 [117312, 133696)       32768 shorts = 16384 dwords
//   Bf2      : s16 [133696, 150080)
//   slots    : [150080, 6572608)          100352*64 = 6,422,528 dwords
//   rec      : u32 [6572608, 8178240)     392*4096 = 1,605,632
//   xb       : u16 [8178240, 11378240)    N*64 u16 = 3,200,000 dwords (12.8MB)
//   mean1    : f32 [11378240, 17778240)   N*64 = 6,400,000 dwords
//   h        : f32 [17778240, 30578240)   N*128 = 12,800,000 dwords
//   q        : f32 [30578240, 36978240)   N*64
// total 36,978,240 dwords = 147.9 MB (round-0 footprint 149.8 MB passed)

// Merged init + weight-split + x->bf16 (one launch).
__global__ __launch_bounds__(256) void prep_kernel(
        const float4* __restrict__ x4, ushort4* __restrict__ xb4,
        const float* __restrict__ W1l, const float* __restrict__ W1r,
        const float* __restrict__ W2l, const float* __restrict__ W2r,
        short* __restrict__ Bf1, short* __restrict__ Bf2,
        int4* __restrict__ gcur4, int* __restrict__ ovfc,
        int* __restrict__ spillc) {
    int i = blockIdx.x * blockDim.x + threadIdx.x;
    if (i < 128) gcur4[i] = make_int4(0, 0, 0, 0);
    if (i == 0) { *ovfc = 0; *spillc = 0; }
    if (i < 32768) {
        int g = i >> 14;
        int e = i & 16383;
        int k = e >> 7;
        int n = e & 127;
        float v;
        if (g == 0) v = (k < 64) ? W1l[k * 128 + n] : W1r[(k - 64) * 128 + n];
        else        v = (n < 64) ? W2l[k * 64 + n]  : W2r[k * 64 + (n - 64)];
        unsigned u = __float_as_uint(v);
        unsigned hb = u >> 16;
        float vh = __uint_as_float(hb << 16);
        unsigned lb = __float_as_uint(v - vh) >> 16;
        int c = n >> 4, kc = k >> 5;
        int lane = (((k >> 3) & 3) << 4) | (n & 15);
        int j = k & 7;
        short* base = g ? Bf2 : Bf1;
        base[((c * 4 + kc) * 2 + 0) * 512 + lane * 8 + j] = (short)hb;
        base[((c * 4 + kc) * 2 + 1) * 512 + lane * 8 + j] = (short)lb;
    }
    if (i < N_NODES * 16) {
        float4 v = x4[i];
        ushort4 o;
        o.x = f2bf(v.x); o.y = f2bf(v.y); o.z = f2bf(v.z); o.w = f2bf(v.w);
        xb4[i] = o;
    }
}

// Pass A: bin edges into 392 dst-range buckets via LDS FIFOs.
// The chip-wide memory-side RMW/scatter-op rate (~24.6G/s measured) is the
// indexing bottleneck; this converts 1M global atomics + 1M scattered
// stores into 1M LDS atomics + ~96K global cursor atomics + compact
// record bursts. Record = (src<<8)|(dst&255), 4B.
__global__ __launch_bounds__(256) void bin_kernel(
        const int* __restrict__ ei, unsigned* __restrict__ rec,
        int* __restrict__ gcur, int* __restrict__ spillc,
        int2* __restrict__ spill) {
    __shared__ int lcnt[NBKT];
    __shared__ unsigned fifo[NBKT * FIFO_CAP];   // 50KB
    for (int i = threadIdx.x; i < NBKT; i += 256) lcnt[i] = 0;
    __syncthreads();
    int base = blockIdx.x * BIN_CHUNK;
    int end = base + BIN_CHUNK;
    if (end > N_EDGES) end = N_EDGES;
    for (int e = base + threadIdx.x; e < end; e += 256) {
        int s = ei[e];
        int d = ei[N_EDGES + e];
        int b = d >> BKT_SH;
        unsigned r = ((unsigned)s << BKT_SH) | (unsigned)(d & (BKT_NODES - 1));
        int pos = atomicAdd(&lcnt[b], 1);
        if (pos < FIFO_CAP) {
            fifo[b * FIFO_CAP + pos] = r;
        } else {                       // ~never (mean 10.4, cap 32)
            int o = atomicAdd(spillc, 1);
            if (o < SPILL_CAP) spill[o] = make_int2(s, d);
        }
    }
    __syncthreads();
    // flush: one thread per bucket; records per bucket are contiguous
    for (int b = threadIdx.x; b < NBKT; b += 256) {
        int cnt = lcnt[b];
        if (cnt > FIFO_CAP) cnt = FIFO_CAP;
        if (cnt == 0) continue;
        int gb = atomicAdd(&gcur[b], cnt);
        for (int k = 0; k < cnt; ++k) {
            int g = gb + k;
            unsigned r = fifo[b * FIFO_CAP + k];
            if (g < BKT_CAP) {
                rec[b * BKT_CAP + g] = r;
            } else {                   // ~never (mean 2551, cap 4096)
                int o = atomicAdd(spillc, 1);
                if (o < SPILL_CAP)
                    spill[o] = make_int2((int)(r >> BKT_SH),
                                         (b << BKT_SH) | (int)(r & (BKT_NODES - 1)));
            }
        }
    }
}

// Pass B: one block per bucket. Build the 256-node counts + slots tile
// entirely in LDS (65KB static -> 2 blocks/CU), then write out fully
// coalesced. Slot positions come from LDS atomics; global writes stream
// at full-line BW instead of 32B-granule scatter ops.
__global__ __launch_bounds__(256) void build_kernel(
        const unsigned* __restrict__ rec, const int* __restrict__ gcur,
        int* __restrict__ counts, int* __restrict__ slots,
        int* __restrict__ ovfc, int* __restrict__ ovf) {
    __shared__ int lcnt[BKT_NODES];
    __shared__ int lslots[BKT_NODES * DEG_CAP];   // 64KB
    int b = blockIdx.x;
    for (int i = threadIdx.x; i < BKT_NODES; i += 256) lcnt[i] = 0;
    __syncthreads();
    int n = gcur[b];
    if (n > BKT_CAP) n = BKT_CAP;
    for (int i = threadIdx.x; i < n; i += 256) {
        unsigned r = rec[b * BKT_CAP + i];
        int dlo = (int)(r & (BKT_NODES - 1));
        int src = (int)(r >> BKT_SH);
        int pos = atomicAdd(&lcnt[dlo], 1);
        if (pos < DEG_CAP) {
            lslots[dlo * DEG_CAP + pos] = src;
        } else {                        // degree>64: overflow funnel (as before)
            int o = atomicAdd(ovfc, 1);
            if (o < OVF_CAP) {
                ovf[o * 2] = src;
                ovf[o * 2 + 1] = (b << BKT_SH) | dlo;
            }
        }
    }
    __syncthreads();
    int nodeBase = b << BKT_SH;
    for (int i = threadIdx.x; i < BKT_NODES; i += 256)
        counts[nodeBase + i] = lcnt[i];
    const int4* ls4 = (const int4*)lslots;
    int4* gs4 = (int4*)(slots + nodeBase * DEG_CAP);
    for (int i = threadIdx.x; i < BKT_NODES * DEG_CAP / 4; i += 256)
        gs4[i] = ls4[i];   // garbage beyond lcnt[d] is never dereferenced
}

// Rare-path spill fix-up: old-style atomic placement (runs after build).
__global__ __launch_bounds__(64) void spill_fix_kernel(
        const int2* __restrict__ spill, const int* __restrict__ spillc,
        int* __restrict__ counts, int* __restrict__ slots,
        int* __restrict__ ovfc, int* __restrict__ ovf) {
    int n = *spillc;
    if (n > SPILL_CAP) n = SPILL_CAP;
    int i = blockIdx.x * 64 + threadIdx.x;
    if (i >= n) return;
    int s = spill[i].x;
    int d = spill[i].y;
    int pos = atomicAdd(&counts[d], 1);
    if (pos < DEG_CAP) {
        slots[d * DEG_CAP + pos] = s;
    } else {
        int o = atomicAdd(ovfc, 1);
        if (o < OVF_CAP) { ovf[o * 2] = s; ovf[o * 2 + 1] = d; }
    }
}

// One wave per node. Lane l: neighbor subgroup l>>4, features (l&15)*4..+3.
__global__ __launch_bounds__(256) void gather_bf_kernel(
        const unsigned short* __restrict__ feat, const int* __restrict__ counts,
        const int* __restrict__ slots, float* __restrict__ agg) {
    int wid = blockIdx.x * 4 + (threadIdx.x >> 6);
    int l = threadIdx.x & 63;
    if (wid >= N_NODES) return;
    int deg = counts[wid];
    int dcap = min(deg, DEG_CAP);
    int ids = slots[wid * DEG_CAP + l];
    const int grp = l >> 4;
    const int fb = (l & 15) * 4;
    float s0 = 0.f, s1 = 0.f, s2 = 0.f, s3 = 0.f;
    int j = 0;
    for (; j + 8 <= dcap; j += 8) {   // grp<=3 -> both neighbors in-range
        int sA = __shfl(ids, j + grp);
        int sB = __shfl(ids, j + 4 + grp);
        uint2 uA = *(const uint2*)(feat + sA * 64 + fb);
        uint2 uB = *(const uint2*)(feat + sB * 64 + fb);
        s0 += bflo(uA.x) + bflo(uB.x);
        s1 += bfhi(uA.x) + bfhi(uB.x);
        s2 += bflo(uA.y) + bflo(uB.y);
        s3 += bfhi(uA.y) + bfhi(uB.y);
    }
    for (; j < dcap; j += 4) {
        int nb = j + grp;
        bool v = nb < dcap;
        int s = __shfl(ids, v ? nb : 0);
        uint2 u = *(const uint2*)(feat + s * 64 + fb);
        if (v) {
            s0 += bflo(u.x);
            s1 += bfhi(u.x);
            s2 += bflo(u.y);
            s3 += bfhi(u.y);
        }
    }
    s0 += __shfl_xor(s0, 16); s0 += __shfl_xor(s0, 32);
    s1 += __shfl_xor(s1, 16); s1 += __shfl_xor(s1, 32);
    s2 += __shfl_xor(s2, 16); s2 += __shfl_xor(s2, 32);
    s3 += __shfl_xor(s3, 16); s3 += __shfl_xor(s3, 32);
    if (l < 16) {
        float inv = 1.0f / fmaxf((float)deg, 1.0f);
        *(float4*)&agg[wid * 64 + fb] =
            make_float4(s0 * inv, s1 * inv, s2 * inv, s3 * inv);
    }
}

// Layer-1 overflow: add x*inv into mean (fp32 x; overflow is ~never hit).
__global__ __launch_bounds__(64) void ovf_scatter_kernel(
        const float* __restrict__ feat, const int* __restrict__ ovf,
        const int* __restrict__ ovfc, const int* __restrict__ counts,
        float* __restrict__ agg) {
    int n = *ovfc;
    if (n > OVF_CAP) n = OVF_CAP;
    for (int idx = blockIdx.x; idx < n; idx += gridDim.x) {
        int s = ovf[idx * 2];
        int d = ovf[idx * 2 + 1];
        float inv = 1.0f / fmaxf((float)counts[d], 1.0f);
        atomicAdd(&agg[d * 64 + threadIdx.x], feat[s * 64 + threadIdx.x] * inv);
    }
}

// Layer 1 MFMA, B-stationary: h = relu( [mean|x] @ [W1l;W1r] + b1 )
__global__ __launch_bounds__(256) void l1_mfma_kernel(
        const float* __restrict__ mean1, const float* __restrict__ x,
        const short* __restrict__ Bf1, const float* __restrict__ b1,
        float* __restrict__ h) {
    const int w = threadIdx.x >> 6;
    const int l = threadIdx.x & 63;
    const int lane15 = l & 15;
    const int quad = l >> 4;
    const int rowBase = blockIdx.x * 128;

    bf16x8 bh[2][4], bl[2][4];
#pragma unroll
    for (int ci = 0; ci < 2; ++ci) {
        const int c = 2 * w + ci;
#pragma unroll
        for (int kc = 0; kc < 4; ++kc) {
            const short* bp = Bf1 + ((c * 4 + kc) * 2) * 512 + l * 8;
            bh[ci][kc] = *(const bf16x8*)bp;
            bl[ci][kc] = *(const bf16x8*)(bp + 512);
        }
    }
    float bias[2];
#pragma unroll
    for (int ci = 0; ci < 2; ++ci) bias[ci] = b1[(2 * w + ci) * 16 + lane15];

#pragma unroll
    for (int rt = 0; rt < 8; ++rt) {
        const int row = rowBase + rt * 16 + lane15;
        const bool rv = row < N_NODES;

        bf16x8 ah[4], al[4];
#pragma unroll
        for (int kc = 0; kc < 4; ++kc) {
            float4 v0 = make_float4(0.f, 0.f, 0.f, 0.f);
            float4 v1 = make_float4(0.f, 0.f, 0.f, 0.f);
            if (rv) {
                const float* src = (kc < 2)
                    ? (mean1 + row * 64 + kc * 32 + quad * 8)
                    : (x     + row * 64 + (kc - 2) * 32 + quad * 8);
                v0 = *(const float4*)src;
                v1 = *(const float4*)(src + 4);
            }
            float f[8] = {v0.x, v0.y, v0.z, v0.w, v1.x, v1.y, v1.z, v1.w};
#pragma unroll
            for (int j = 0; j < 8; ++j) {
                unsigned u = __float_as_uint(f[j]);
                unsigned hb = u >> 16;
                float fh = __uint_as_float(hb << 16);
                unsigned lb = __float_as_uint(f[j] - fh) >> 16;
                ah[kc][j] = (short)hb;
                al[kc][j] = (short)lb;
            }
        }

        f32x4 acc[2] = {(f32x4){0.f, 0.f, 0.f, 0.f}, (f32x4){0.f, 0.f, 0.f, 0.f}};
#pragma unroll
        for (int kc = 0; kc < 4; ++kc) {
#pragma unroll
            for (int ci = 0; ci < 2; ++ci) {
                acc[ci] = __builtin_amdgcn_mfma_f32_16x16x32_bf16(ah[kc], bh[ci][kc], acc[ci], 0, 0, 0);
                acc[ci] = __builtin_amdgcn_mfma_f32_16x16x32_bf16(al[kc], bh[ci][kc], acc[ci], 0, 0, 0);
                acc[ci] = __builtin_amdgcn_mfma_f32_16x16x32_bf16(ah[kc], bl[ci][kc], acc[ci], 0, 0, 0);
            }
        }

        const int rb = rowBase + rt * 16 + quad * 4;
#pragma unroll
        for (int ci = 0; ci < 2; ++ci) {
            const int col = (2 * w + ci) * 16 + lane15;
#pragma unroll
            for (int i = 0; i < 4; ++i) {
                int r = rb + i;
                if (r < N_NODES)
                    h[r * 128 + col] = fmaxf(acc[ci][i] + bias[ci], 0.f);
            }
        }
    }
}

// Layer 2 MFMA, B-stationary: p(bf16) = h @ W2l ; q(fp32) = h @ W2r + b2
__global__ __launch_bounds__(256) void l2_mfma_kernel(
        const float* __restrict__ h, const short* __restrict__ Bf2,
        const float* __restrict__ b2,
        unsigned short* __restrict__ p_bf, float* __restrict__ q) {
    const int w = threadIdx.x >> 6;
    const int l = threadIdx.x & 63;
    const int lane15 = l & 15;
    const int quad = l >> 4;
    const int rowBase = blockIdx.x * 128;

    bf16x8 bh[2][4], bl[2][4];
#pragma unroll
    for (int ci = 0; ci < 2; ++ci) {
        const int c = 2 * w + ci;
#pragma unroll
        for (int kc = 0; kc < 4; ++kc) {
            const short* bp = Bf2 + ((c * 4 + kc) * 2) * 512 + l * 8;
            bh[ci][kc] = *(const bf16x8*)bp;
            bl[ci][kc] = *(const bf16x8*)(bp + 512);
        }
    }
    float bias[2];
#pragma unroll
    for (int ci = 0; ci < 2; ++ci) {
        const int c = 2 * w + ci;
        bias[ci] = (c >= 4) ? b2[(c - 4) * 16 + lane15] : 0.f;
    }

#pragma unroll
    for (int rt = 0; rt < 8; ++rt) {
        const int row = rowBase + rt * 16 + lane15;
        const bool rv = row < N_NODES;

        bf16x8 ah[4], al[4];
#pragma unroll
        for (int kc = 0; kc < 4; ++kc) {
            float4 v0 = make_float4(0.f, 0.f, 0.f, 0.f);
            float4 v1 = make_float4(0.f, 0.f, 0.f, 0.f);
            if (rv) {
                const float* src = h + row * 128 + kc * 32 + quad * 8;
                v0 = *(const float4*)src;
                v1 = *(const float4*)(src + 4);
            }
            float f[8] = {v0.x, v0.y, v0.z, v0.w, v1.x, v1.y, v1.z, v1.w};
#pragma unroll
            for (int j = 0; j < 8; ++j) {
                unsigned u = __float_as_uint(f[j]);
                unsigned hb = u >> 16;
                float fh = __uint_as_float(hb << 16);
                unsigned lb = __float_as_uint(f[j] - fh) >> 16;
                ah[kc][j] = (short)hb;
                al[kc][j] = (short)lb;
            }
        }

        f32x4 acc[2] = {(f32x4){0.f, 0.f, 0.f, 0.f}, (f32x4){0.f, 0.f, 0.f, 0.f}};
#pragma unroll
        for (int kc = 0; kc < 4; ++kc) {
#pragma unroll
            for (int ci = 0; ci < 2; ++ci) {
                acc[ci] = __builtin_amdgcn_mfma_f32_16x16x32_bf16(ah[kc], bh[ci][kc], acc[ci], 0, 0, 0);
                acc[ci] = __builtin_amdgcn_mfma_f32_16x16x32_bf16(al[kc], bh[ci][kc], acc[ci], 0, 0, 0);
                acc[ci] = __builtin_amdgcn_mfma_f32_16x16x32_bf16(ah[kc], bl[ci][kc], acc[ci], 0, 0, 0);
            }
        }

        const int rb = rowBase + rt * 16 + quad * 4;
#pragma unroll
        for (int ci = 0; ci < 2; ++ci) {
            const int c = 2 * w + ci;
            if (c < 4) {
#pragma unroll
                for (int i = 0; i < 4; ++i) {
                    int r = rb + i;
                    if (r < N_NODES)
                        p_bf[r * 64 + c * 16 + lane15] = f2bf(acc[ci][i]);
                }
            } else {
#pragma unroll
                for (int i = 0; i < 4; ++i) {
                    int r = rb + i;
                    if (r < N_NODES)
                        q[r * 64 + (c - 4) * 16 + lane15] = acc[ci][i] + bias[ci];
                }
            }
        }
    }
}

// Fused layer-2 aggregation + epilogue: out = mean(p_bf[nbrs]) + q
__global__ __launch_bounds__(256) void gather_final_kernel(
        const unsigned short* __restrict__ p, const int* __restrict__ counts,
        const int* __restrict__ slots, const float* __restrict__ q,
        float* __restrict__ out) {
    int wid = blockIdx.x * 4 + (threadIdx.x >> 6);
    int l = threadIdx.x & 63;
    if (wid >= N_NODES) return;
    int deg = counts[wid];
    int dcap = min(deg, DEG_CAP);
    int ids = slots[wid * DEG_CAP + l];
    const int grp = l >> 4;
    const int fb = (l & 15) * 4;
    float s0 = 0.f, s1 = 0.f, s2 = 0.f, s3 = 0.f;
    int j = 0;
    for (; j + 8 <= dcap; j += 8) {
        int sA = __shfl(ids, j + grp);
        int sB = __shfl(ids, j + 4 + grp);
        uint2 uA = *(const uint2*)(p + sA * 64 + fb);
        uint2 uB = *(const uint2*)(p + sB * 64 + fb);
        s0 += bflo(uA.x) + bflo(uB.x);
        s1 += bfhi(uA.x) + bfhi(uB.x);
        s2 += bflo(uA.y) + bflo(uB.y);
        s3 += bfhi(uA.y) + bfhi(uB.y);
    }
    for (; j < dcap; j += 4) {
        int nb = j + grp;
        bool v = nb < dcap;
        int s = __shfl(ids, v ? nb : 0);
        uint2 u = *(const uint2*)(p + s * 64 + fb);
        if (v) {
            s0 += bflo(u.x);
            s1 += bfhi(u.x);
            s2 += bflo(u.y);
            s3 += bfhi(u.y);
        }
    }
    s0 += __shfl_xor(s0, 16); s0 += __shfl_xor(s0, 32);
    s1 += __shfl_xor(s1, 16); s1 += __shfl_xor(s1, 32);
    s2 += __shfl_xor(s2, 16); s2 += __shfl_xor(s2, 32);
    s3 += __shfl_xor(s3, 16); s3 += __shfl_xor(s3, 32);
    if (l < 16) {
        float inv = 1.0f / fmaxf((float)deg, 1.0f);
        float4 qv = *(const float4*)&q[wid * 64 + fb];
        *(float4*)&out[wid * 64 + fb] =
            make_float4(s0 * inv + qv.x, s1 * inv + qv.y,
                        s2 * inv + qv.z, s3 * inv + qv.w);
    }
}

// Layer-2 overflow fix-up (additive).
__global__ __launch_bounds__(64) void ovf_fixup_kernel(
        const unsigned short* __restrict__ p, const int* __restrict__ ovf,
        const int* __restrict__ ovfc, const int* __restrict__ counts,
        float* __restrict__ out) {
    int n = *ovfc;
    if (n > OVF_CAP) n = OVF_CAP;
    for (int idx = blockIdx.x; idx < n; idx += gridDim.x) {
        int s = ovf[idx * 2];
        int d = ovf[idx * 2 + 1];
        float inv = 1.0f / fmaxf((float)counts[d], 1.0f);
        atomicAdd(&out[d * 64 + threadIdx.x],
                  bf2f(p[s * 64 + threadIdx.x]) * inv);
    }
}

extern "C" void kernel_launch(void* const* d_in, const int* in_sizes, int n_in,
                              void* d_out, int out_size, void* d_ws, size_t ws_size,
                              hipStream_t stream) {
    const float* x   = (const float*)d_in[0];
    const float* W1l = (const float*)d_in[1];
    const float* W1r = (const float*)d_in[2];
    const float* b1  = (const float*)d_in[3];
    const float* W2l = (const float*)d_in[4];
    const float* W2r = (const float*)d_in[5];
    const float* b2  = (const float*)d_in[6];
    const int*   ei  = (const int*)d_in[7];

    int*   wsi      = (int*)d_ws;
    float* wsf      = (float*)d_ws;
    int*   counts   = wsi;
    int*   ovfc     = wsi + 100352;
    int*   spillc   = wsi + 100353;
    int*   gcur     = wsi + 100416;
    int*   ovf      = wsi + 100928;
    int2*  spill    = (int2*)(wsi + 109120);
    short* Bf1      = (short*)(wsi + 117312);
    short* Bf2      = (short*)(wsi + 133696);
    int*   slots    = wsi + 150080;
    unsigned* rec   = (unsigned*)(wsi + 6572608);
    unsigned short* xb = (unsigned short*)(wsi + 8178240);
    float* mean1    = wsf + 11378240;
    unsigned short* p_bf = (unsigned short*)(wsf + 11378240);  // reuse after l1
    float* h        = wsf + 17778240;
    float* q        = wsf + 30578240;
    float* out      = (float*)d_out;

    prep_kernel<<<(N_NODES * 16 + 255) / 256, 256, 0, stream>>>(
        (const float4*)x, (ushort4*)xb, W1l, W1r, W2l, W2r, Bf1, Bf2,
        (int4*)gcur, ovfc, spillc);

    // indexing: LDS-binned two-pass (replaces 1M-global-atomic histfill)
    bin_kernel<<<(N_EDGES + BIN_CHUNK - 1) / BIN_CHUNK, 256, 0, stream>>>(
        ei, rec, gcur, spillc, spill);
    build_kernel<<<NBKT, 256, 0, stream>>>(rec, gcur, counts, slots, ovfc, ovf);
    spill_fix_kernel<<<SPILL_CAP / 64, 64, 0, stream>>>(
        spill, spillc, counts, slots, ovfc, ovf);

    // layer-1 aggregation -> mean (bf16 rows), + overflow
    gather_bf_kernel<<<(N_NODES + 3) / 4, 256, 0, stream>>>(xb, counts, slots, mean1);
    ovf_scatter_kernel<<<64, 64, 0, stream>>>(x, ovf, ovfc, counts, mean1);

    // h = relu([mean|x] @ [W1l;W1r] + b1)
    l1_mfma_kernel<<<(N_NODES + 127) / 128, 256, 0, stream>>>(
        mean1, x, Bf1, b1, h);
    // p(bf16) = h @ W2l ; q = h @ W2r + b2   (p_bf overwrites mean1)
    l2_mfma_kernel<<<(N_NODES + 127) / 128, 256, 0, stream>>>(h, Bf2, b2, p_bf, q);

    // fused layer-2 aggregation + epilogue, then overflow fix-up
    gather_final_kernel<<<(N_NODES + 3) / 4, 256, 0, stream>>>(
        p_bf, counts, slots, q, out);
    ovf_fixup_kernel<<<64, 64, 0, stream>>>(p_bf, ovf, ovfc, counts, out);
}

// Round 5
// 229.034 us; speedup vs baseline: 1.3821x; 1.1164x over previous
//
#include <hip/hip_runtime.h>

#define N_NODES 100000
#define N_EDGES 1000000
#define DEG_CAP 64
#define OVF_CAP 4096
#define SPILL_CAP 4096

// binning geometry
#define BKT_SH 8
#define BKT_NODES 256            // nodes per bucket
#define NBKT 392                 // 392*256 = 100352 >= N_NODES
#define BKT_CAP 4096             // record capacity per bucket (mean ~2551)
#define BIN_CHUNK 4096           // edges per bin block
#define FIFO_CAP 32              // LDS fifo depth per bucket (mean ~10.4)

typedef __attribute__((ext_vector_type(8))) short bf16x8;
typedef __attribute__((ext_vector_type(4))) float f32x4;

__device__ __forceinline__ unsigned short f2bf(float f) {
    unsigned u = __float_as_uint(f);
    return (unsigned short)((u + 0x7FFF + ((u >> 16) & 1)) >> 16);
}
__device__ __forceinline__ float bf2f(unsigned short b) {
    return __uint_as_float(((unsigned)b) << 16);
}
__device__ __forceinline__ float bflo(unsigned u) {   // low bf16 of a dword
    return __uint_as_float(u << 16);
}
__device__ __forceinline__ float bfhi(unsigned u) {   // high bf16 of a dword
    return __uint_as_float(u & 0xffff0000u);
}

// ws layout (4B units) — AUDITED SIZES:
//   counts   : int [0, 100352)
//   ovfc     : 100352 ; spillc : 100353
//   gcur     : [100416, 100928)           512 ints (392 used)
//   ovf      : [100928, 109120)           2*4096
//   spill    : [109120, 117312)           4096 int2
//   Bf1      : s16 [117312, 133696)       32768 shorts = 16384 dwords
//   Bf2      : s16 [133696, 150080)
//   slots    : [150080, 6572608)          100352*64 = 6,422,528 dwords
//   rec      : u32 [6572608, 8178240)     392*4096 = 1,605,632
//   xb       : u16 [8178240, 11378240)    N*64 u16 = 3,200,000 dwords
//   mean1    : f32 [11378240, 17778240)   N*64 = 6,400,000 dwords
//   p_bf     : u16 [17778240, 20978240)   N*64 u16 (own region — fused kernel
//                                         must NOT alias mean1: cross-block race)
//   q        : f32 [30578240, 36978240)   N*64
// total <= 36,978,240 dwords = 147.9 MB (unchanged envelope)

// Merged init + weight-split + x->bf16 (one launch).
__global__ __launch_bounds__(256) void prep_kernel(
        const float4* __restrict__ x4, ushort4* __restrict__ xb4,
        const float* __restrict__ W1l, const float* __restrict__ W1r,
        const float* __restrict__ W2l, const float* __restrict__ W2r,
        short* __restrict__ Bf1, short* __restrict__ Bf2,
        int4* __restrict__ gcur4, int* __restrict__ ovfc,
        int* __restrict__ spillc) {
    int i = blockIdx.x * blockDim.x + threadIdx.x;
    if (i < 128) gcur4[i] = make_int4(0, 0, 0, 0);
    if (i == 0) { *ovfc = 0; *spillc = 0; }
    if (i < 32768) {
        int g = i >> 14;
        int e = i & 16383;
        int k = e >> 7;
        int n = e & 127;
        float v;
        if (g == 0) v = (k < 64) ? W1l[k * 128 + n] : W1r[(k - 64) * 128 + n];
        else        v = (n < 64) ? W2l[k * 64 + n]  : W2r[k * 64 + (n - 64)];
        unsigned u = __float_as_uint(v);
        unsigned hb = u >> 16;
        float vh = __uint_as_float(hb << 16);
        unsigned lb = __float_as_uint(v - vh) >> 16;
        int c = n >> 4, kc = k >> 5;
        int lane = (((k >> 3) & 3) << 4) | (n & 15);
        int j = k & 7;
        short* base = g ? Bf2 : Bf1;
        base[((c * 4 + kc) * 2 + 0) * 512 + lane * 8 + j] = (short)hb;
        base[((c * 4 + kc) * 2 + 1) * 512 + lane * 8 + j] = (short)lb;
    }
    if (i < N_NODES * 16) {
        float4 v = x4[i];
        ushort4 o;
        o.x = f2bf(v.x); o.y = f2bf(v.y); o.z = f2bf(v.z); o.w = f2bf(v.w);
        xb4[i] = o;
    }
}

// Pass A: bin edges into 392 dst-range buckets via LDS FIFOs.
__global__ __launch_bounds__(256) void bin_kernel(
        const int* __restrict__ ei, unsigned* __restrict__ rec,
        int* __restrict__ gcur, int* __restrict__ spillc,
        int2* __restrict__ spill) {
    __shared__ int lcnt[NBKT];
    __shared__ unsigned fifo[NBKT * FIFO_CAP];   // 50KB
    for (int i = threadIdx.x; i < NBKT; i += 256) lcnt[i] = 0;
    __syncthreads();
    int base = blockIdx.x * BIN_CHUNK;
    int end = base + BIN_CHUNK;
    if (end > N_EDGES) end = N_EDGES;
    for (int e = base + threadIdx.x; e < end; e += 256) {
        int s = ei[e];
        int d = ei[N_EDGES + e];
        int b = d >> BKT_SH;
        unsigned r = ((unsigned)s << BKT_SH) | (unsigned)(d & (BKT_NODES - 1));
        int pos = atomicAdd(&lcnt[b], 1);
        if (pos < FIFO_CAP) {
            fifo[b * FIFO_CAP + pos] = r;
        } else {
            int o = atomicAdd(spillc, 1);
            if (o < SPILL_CAP) spill[o] = make_int2(s, d);
        }
    }
    __syncthreads();
    for (int b = threadIdx.x; b < NBKT; b += 256) {
        int cnt = lcnt[b];
        if (cnt > FIFO_CAP) cnt = FIFO_CAP;
        if (cnt == 0) continue;
        int gb = atomicAdd(&gcur[b], cnt);
        for (int k = 0; k < cnt; ++k) {
            int g = gb + k;
            unsigned r = fifo[b * FIFO_CAP + k];
            if (g < BKT_CAP) {
                rec[b * BKT_CAP + g] = r;
            } else {
                int o = atomicAdd(spillc, 1);
                if (o < SPILL_CAP)
                    spill[o] = make_int2((int)(r >> BKT_SH),
                                         (b << BKT_SH) | (int)(r & (BKT_NODES - 1)));
            }
        }
    }
}

// Pass B: one block per bucket; counts + slots tile built in LDS (65KB),
// written out fully coalesced.
__global__ __launch_bounds__(256) void build_kernel(
        const unsigned* __restrict__ rec, const int* __restrict__ gcur,
        int* __restrict__ counts, int* __restrict__ slots,
        int* __restrict__ ovfc, int* __restrict__ ovf) {
    __shared__ int lcnt[BKT_NODES];
    __shared__ int lslots[BKT_NODES * DEG_CAP];   // 64KB
    int b = blockIdx.x;
    for (int i = threadIdx.x; i < BKT_NODES; i += 256) lcnt[i] = 0;
    __syncthreads();
    int n = gcur[b];
    if (n > BKT_CAP) n = BKT_CAP;
    for (int i = threadIdx.x; i < n; i += 256) {
        unsigned r = rec[b * BKT_CAP + i];
        int dlo = (int)(r & (BKT_NODES - 1));
        int src = (int)(r >> BKT_SH);
        int pos = atomicAdd(&lcnt[dlo], 1);
        if (pos < DEG_CAP) {
            lslots[dlo * DEG_CAP + pos] = src;
        } else {
            int o = atomicAdd(ovfc, 1);
            if (o < OVF_CAP) {
                ovf[o * 2] = src;
                ovf[o * 2 + 1] = (b << BKT_SH) | dlo;
            }
        }
    }
    __syncthreads();
    int nodeBase = b << BKT_SH;
    for (int i = threadIdx.x; i < BKT_NODES; i += 256)
        counts[nodeBase + i] = lcnt[i];
    const int4* ls4 = (const int4*)lslots;
    int4* gs4 = (int4*)(slots + nodeBase * DEG_CAP);
    for (int i = threadIdx.x; i < BKT_NODES * DEG_CAP / 4; i += 256)
        gs4[i] = ls4[i];
}

// Rare-path spill fix-up.
__global__ __launch_bounds__(64) void spill_fix_kernel(
        const int2* __restrict__ spill, const int* __restrict__ spillc,
        int* __restrict__ counts, int* __restrict__ slots,
        int* __restrict__ ovfc, int* __restrict__ ovf) {
    int n = *spillc;
    if (n > SPILL_CAP) n = SPILL_CAP;
    int i = blockIdx.x * 64 + threadIdx.x;
    if (i >= n) return;
    int s = spill[i].x;
    int d = spill[i].y;
    int pos = atomicAdd(&counts[d], 1);
    if (pos < DEG_CAP) {
        slots[d * DEG_CAP + pos] = s;
    } else {
        int o = atomicAdd(ovfc, 1);
        if (o < OVF_CAP) { ovf[o * 2] = s; ovf[o * 2 + 1] = d; }
    }
}

// One wave per node. Lane l: neighbor subgroup l>>4, features (l&15)*4..+3.
__global__ __launch_bounds__(256) void gather_bf_kernel(
        const unsigned short* __restrict__ feat, const int* __restrict__ counts,
        const int* __restrict__ slots, float* __restrict__ agg) {
    int wid = blockIdx.x * 4 + (threadIdx.x >> 6);
    int l = threadIdx.x & 63;
    if (wid >= N_NODES) return;
    int deg = counts[wid];
    int dcap = min(deg, DEG_CAP);
    int ids = slots[wid * DEG_CAP + l];
    const int grp = l >> 4;
    const int fb = (l & 15) * 4;
    float s0 = 0.f, s1 = 0.f, s2 = 0.f, s3 = 0.f;
    int j = 0;
    for (; j + 8 <= dcap; j += 8) {
        int sA = __shfl(ids, j + grp);
        int sB = __shfl(ids, j + 4 + grp);
        uint2 uA = *(const uint2*)(feat + sA * 64 + fb);
        uint2 uB = *(const uint2*)(feat + sB * 64 + fb);
        s0 += bflo(uA.x) + bflo(uB.x);
        s1 += bfhi(uA.x) + bfhi(uB.x);
        s2 += bflo(uA.y) + bflo(uB.y);
        s3 += bfhi(uA.y) + bfhi(uB.y);
    }
    for (; j < dcap; j += 4) {
        int nb = j + grp;
        bool v = nb < dcap;
        int s = __shfl(ids, v ? nb : 0);
        uint2 u = *(const uint2*)(feat + s * 64 + fb);
        if (v) {
            s0 += bflo(u.x);
            s1 += bfhi(u.x);
            s2 += bflo(u.y);
            s3 += bfhi(u.y);
        }
    }
    s0 += __shfl_xor(s0, 16); s0 += __shfl_xor(s0, 32);
    s1 += __shfl_xor(s1, 16); s1 += __shfl_xor(s1, 32);
    s2 += __shfl_xor(s2, 16); s2 += __shfl_xor(s2, 32);
    s3 += __shfl_xor(s3, 16); s3 += __shfl_xor(s3, 32);
    if (l < 16) {
        float inv = 1.0f / fmaxf((float)deg, 1.0f);
        *(float4*)&agg[wid * 64 + fb] =
            make_float4(s0 * inv, s1 * inv, s2 * inv, s3 * inv);
    }
}

// Layer-1 overflow: add x*inv into mean.
__global__ __launch_bounds__(64) void ovf_scatter_kernel(
        const float* __restrict__ feat, const int* __restrict__ ovf,
        const int* __restrict__ ovfc, const int* __restrict__ counts,
        float* __restrict__ agg) {
    int n = *ovfc;
    if (n > OVF_CAP) n = OVF_CAP;
    for (int idx = blockIdx.x; idx < n; idx += gridDim.x) {
        int s = ovf[idx * 2];
        int d = ovf[idx * 2 + 1];
        float inv = 1.0f / fmaxf((float)counts[d], 1.0f);
        atomicAdd(&agg[d * 64 + threadIdx.x], feat[s * 64 + threadIdx.x] * inv);
    }
}

// FUSED MLP: h = relu([mean|x]@[W1l;W1r]+b1) staged as bf16 in LDS, then
// p(bf16) = h@W2l ; q = h@W2r + b2 — h never touches global memory.
// Eliminates 51.2MB h-write + 51.2MB h-read and l2's entire fp32->hi/lo
// split pass (phase 2 ds_read_b128's bf16 fragments directly).
// Padded LDS row (136 bf16 = 272B = 17*16B) rotates banks: b128 reads are
// effectively conflict-free, b16 writes ~2-way (free per m136).
__global__ __launch_bounds__(256) void mlp_fused_kernel(
        const float* __restrict__ mean1, const float* __restrict__ x,
        const short* __restrict__ Bf1, const float* __restrict__ b1,
        const short* __restrict__ Bf2, const float* __restrict__ b2,
        unsigned short* __restrict__ p_bf, float* __restrict__ q) {
    __shared__ unsigned short h_lds[128][136];   // 34816 B
    const int w = threadIdx.x >> 6;
    const int l = threadIdx.x & 63;
    const int lane15 = l & 15;
    const int quad = l >> 4;
    const int rowBase = blockIdx.x * 128;

    // ---- phase 1: layer 1, B-stationary, 3-MFMA hi/lo split ----
    {
        bf16x8 bh[2][4], bl[2][4];
#pragma unroll
        for (int ci = 0; ci < 2; ++ci) {
            const int c = 2 * w + ci;
#pragma unroll
            for (int kc = 0; kc < 4; ++kc) {
                const short* bp = Bf1 + ((c * 4 + kc) * 2) * 512 + l * 8;
                bh[ci][kc] = *(const bf16x8*)bp;
                bl[ci][kc] = *(const bf16x8*)(bp + 512);
            }
        }
        float bias[2];
#pragma unroll
        for (int ci = 0; ci < 2; ++ci) bias[ci] = b1[(2 * w + ci) * 16 + lane15];

#pragma unroll
        for (int rt = 0; rt < 8; ++rt) {
            const int row = rowBase + rt * 16 + lane15;
            const bool rv = row < N_NODES;

            bf16x8 ah[4], al[4];
#pragma unroll
            for (int kc = 0; kc < 4; ++kc) {
                float4 v0 = make_float4(0.f, 0.f, 0.f, 0.f);
                float4 v1 = make_float4(0.f, 0.f, 0.f, 0.f);
                if (rv) {
                    const float* src = (kc < 2)
                        ? (mean1 + row * 64 + kc * 32 + quad * 8)
                        : (x     + row * 64 + (kc - 2) * 32 + quad * 8);
                    v0 = *(const float4*)src;
                    v1 = *(const float4*)(src + 4);
                }
                float f[8] = {v0.x, v0.y, v0.z, v0.w, v1.x, v1.y, v1.z, v1.w};
#pragma unroll
                for (int j = 0; j < 8; ++j) {
                    unsigned u = __float_as_uint(f[j]);
                    unsigned hb = u >> 16;
                    float fh = __uint_as_float(hb << 16);
                    unsigned lb = __float_as_uint(f[j] - fh) >> 16;
                    ah[kc][j] = (short)hb;
                    al[kc][j] = (short)lb;
                }
            }

            f32x4 acc[2] = {(f32x4){0.f, 0.f, 0.f, 0.f}, (f32x4){0.f, 0.f, 0.f, 0.f}};
#pragma unroll
            for (int kc = 0; kc < 4; ++kc) {
#pragma unroll
                for (int ci = 0; ci < 2; ++ci) {
                    acc[ci] = __builtin_amdgcn_mfma_f32_16x16x32_bf16(ah[kc], bh[ci][kc], acc[ci], 0, 0, 0);
                    acc[ci] = __builtin_amdgcn_mfma_f32_16x16x32_bf16(al[kc], bh[ci][kc], acc[ci], 0, 0, 0);
                    acc[ci] = __builtin_amdgcn_mfma_f32_16x16x32_bf16(ah[kc], bl[ci][kc], acc[ci], 0, 0, 0);
                }
            }

            // C layout: col = c*16+lane15, local row = rt*16 + quad*4 + i
            const int rloc = rt * 16 + quad * 4;
#pragma unroll
            for (int ci = 0; ci < 2; ++ci) {
                const int col = (2 * w + ci) * 16 + lane15;
#pragma unroll
                for (int i = 0; i < 4; ++i)
                    h_lds[rloc + i][col] =
                        f2bf(fmaxf(acc[ci][i] + bias[ci], 0.f));
            }
        }
    }
    __syncthreads();

    // ---- phase 2: layer 2 from LDS (A = bf16, W2 keeps hi/lo split) ----
    {
        bf16x8 bh[2][4], bl[2][4];
#pragma unroll
        for (int ci = 0; ci < 2; ++ci) {
            const int c = 2 * w + ci;
#pragma unroll
            for (int kc = 0; kc < 4; ++kc) {
                const short* bp = Bf2 + ((c * 4 + kc) * 2) * 512 + l * 8;
                bh[ci][kc] = *(const bf16x8*)bp;
                bl[ci][kc] = *(const bf16x8*)(bp + 512);
            }
        }
        float bias[2];
#pragma unroll
        for (int ci = 0; ci < 2; ++ci) {
            const int c = 2 * w + ci;
            bias[ci] = (c >= 4) ? b2[(c - 4) * 16 + lane15] : 0.f;
        }

#pragma unroll
        for (int rt = 0; rt < 8; ++rt) {
            bf16x8 ah[4];
#pragma unroll
            for (int kc = 0; kc < 4; ++kc)
                ah[kc] = *(const bf16x8*)&h_lds[rt * 16 + lane15][kc * 32 + quad * 8];

            f32x4 acc[2] = {(f32x4){0.f, 0.f, 0.f, 0.f}, (f32x4){0.f, 0.f, 0.f, 0.f}};
#pragma unroll
            for (int kc = 0; kc < 4; ++kc) {
#pragma unroll
                for (int ci = 0; ci < 2; ++ci) {
                    acc[ci] = __builtin_amdgcn_mfma_f32_16x16x32_bf16(ah[kc], bh[ci][kc], acc[ci], 0, 0, 0);
                    acc[ci] = __builtin_amdgcn_mfma_f32_16x16x32_bf16(ah[kc], bl[ci][kc], acc[ci], 0, 0, 0);
                }
            }

            const int rb = rowBase + rt * 16 + quad * 4;
#pragma unroll
            for (int ci = 0; ci < 2; ++ci) {
                const int c = 2 * w + ci;
                if (c < 4) {
#pragma unroll
                    for (int i = 0; i < 4; ++i) {
                        int r = rb + i;
                        if (r < N_NODES)
                            p_bf[r * 64 + c * 16 + lane15] = f2bf(acc[ci][i]);
                    }
                } else {
#pragma unroll
                    for (int i = 0; i < 4; ++i) {
                        int r = rb + i;
                        if (r < N_NODES)
                            q[r * 64 + (c - 4) * 16 + lane15] = acc[ci][i] + bias[ci];
                    }
                }
            }
        }
    }
}

// Fused layer-2 aggregation + epilogue: out = mean(p_bf[nbrs]) + q
__global__ __launch_bounds__(256) void gather_final_kernel(
        const unsigned short* __restrict__ p, const int* __restrict__ counts,
        const int* __restrict__ slots, const float* __restrict__ q,
        float* __restrict__ out) {
    int wid = blockIdx.x * 4 + (threadIdx.x >> 6);
    int l = threadIdx.x & 63;
    if (wid >= N_NODES) return;
    int deg = counts[wid];
    int dcap = min(deg, DEG_CAP);
    int ids = slots[wid * DEG_CAP + l];
    const int grp = l >> 4;
    const int fb = (l & 15) * 4;
    float s0 = 0.f, s1 = 0.f, s2 = 0.f, s3 = 0.f;
    int j = 0;
    for (; j + 8 <= dcap; j += 8) {
        int sA = __shfl(ids, j + grp);
        int sB = __shfl(ids, j + 4 + grp);
        uint2 uA = *(const uint2*)(p + sA * 64 + fb);
        uint2 uB = *(const uint2*)(p + sB * 64 + fb);
        s0 += bflo(uA.x) + bflo(uB.x);
        s1 += bfhi(uA.x) + bfhi(uB.x);
        s2 += bflo(uA.y) + bflo(uB.y);
        s3 += bfhi(uA.y) + bfhi(uB.y);
    }
    for (; j < dcap; j += 4) {
        int nb = j + grp;
        bool v = nb < dcap;
        int s = __shfl(ids, v ? nb : 0);
        uint2 u = *(const uint2*)(p + s * 64 + fb);
        if (v) {
            s0 += bflo(u.x);
            s1 += bfhi(u.x);
            s2 += bflo(u.y);
            s3 += bfhi(u.y);
        }
    }
    s0 += __shfl_xor(s0, 16); s0 += __shfl_xor(s0, 32);
    s1 += __shfl_xor(s1, 16); s1 += __shfl_xor(s1, 32);
    s2 += __shfl_xor(s2, 16); s2 += __shfl_xor(s2, 32);
    s3 += __shfl_xor(s3, 16); s3 += __shfl_xor(s3, 32);
    if (l < 16) {
        float inv = 1.0f / fmaxf((float)deg, 1.0f);
        float4 qv = *(const float4*)&q[wid * 64 + fb];
        *(float4*)&out[wid * 64 + fb] =
            make_float4(s0 * inv + qv.x, s1 * inv + qv.y,
                        s2 * inv + qv.z, s3 * inv + qv.w);
    }
}

// Layer-2 overflow fix-up (additive).
__global__ __launch_bounds__(64) void ovf_fixup_kernel(
        const unsigned short* __restrict__ p, const int* __restrict__ ovf,
        const int* __restrict__ ovfc, const int* __restrict__ counts,
        float* __restrict__ out) {
    int n = *ovfc;
    if (n > OVF_CAP) n = OVF_CAP;
    for (int idx = blockIdx.x; idx < n; idx += gridDim.x) {
        int s = ovf[idx * 2];
        int d = ovf[idx * 2 + 1];
        float inv = 1.0f / fmaxf((float)counts[d], 1.0f);
        atomicAdd(&out[d * 64 + threadIdx.x],
                  bf2f(p[s * 64 + threadIdx.x]) * inv);
    }
}

extern "C" void kernel_launch(void* const* d_in, const int* in_sizes, int n_in,
                              void* d_out, int out_size, void* d_ws, size_t ws_size,
                              hipStream_t stream) {
    const float* x   = (const float*)d_in[0];
    const float* W1l = (const float*)d_in[1];
    const float* W1r = (const float*)d_in[2];
    const float* b1  = (const float*)d_in[3];
    const float* W2l = (const float*)d_in[4];
    const float* W2r = (const float*)d_in[5];
    const float* b2  = (const float*)d_in[6];
    const int*   ei  = (const int*)d_in[7];

    int*   wsi      = (int*)d_ws;
    float* wsf      = (float*)d_ws;
    int*   counts   = wsi;
    int*   ovfc     = wsi + 100352;
    int*   spillc   = wsi + 100353;
    int*   gcur     = wsi + 100416;
    int*   ovf      = wsi + 100928;
    int2*  spill    = (int2*)(wsi + 109120);
    short* Bf1      = (short*)(wsi + 117312);
    short* Bf2      = (short*)(wsi + 133696);
    int*   slots    = wsi + 150080;
    unsigned* rec   = (unsigned*)(wsi + 6572608);
    unsigned short* xb = (unsigned short*)(wsi + 8178240);
    float* mean1    = wsf + 11378240;
    unsigned short* p_bf = (unsigned short*)(wsf + 17778240);  // own region!
    float* q        = wsf + 30578240;
    float* out      = (float*)d_out;

    prep_kernel<<<(N_NODES * 16 + 255) / 256, 256, 0, stream>>>(
        (const float4*)x, (ushort4*)xb, W1l, W1r, W2l, W2r, Bf1, Bf2,
        (int4*)gcur, ovfc, spillc);

    // indexing: LDS-binned two-pass
    bin_kernel<<<(N_EDGES + BIN_CHUNK - 1) / BIN_CHUNK, 256, 0, stream>>>(
        ei, rec, gcur, spillc, spill);
    build_kernel<<<NBKT, 256, 0, stream>>>(rec, gcur, counts, slots, ovfc, ovf);
    spill_fix_kernel<<<SPILL_CAP / 64, 64, 0, stream>>>(
        spill, spillc, counts, slots, ovfc, ovf);

    // layer-1 aggregation -> mean (bf16 rows), + overflow
    gather_bf_kernel<<<(N_NODES + 3) / 4, 256, 0, stream>>>(xb, counts, slots, mean1);
    ovf_scatter_kernel<<<64, 64, 0, stream>>>(x, ovf, ovfc, counts, mean1);

    // fused: h (LDS) -> p_bf, q in one pass
    mlp_fused_kernel<<<(N_NODES + 127) / 128, 256, 0, stream>>>(
        mean1, x, Bf1, b1, Bf2, b2, p_bf, q);

    // fused layer-2 aggregation + epilogue, then overflow fix-up
    gather_final_kernel<<<(N_NODES + 3) / 4, 256, 0, stream>>>(
        p_bf, counts, slots, q, out);
    ovf_fixup_kernel<<<64, 64, 0, stream>>>(p_bf, ovf, ovfc, counts, out);
}

// Round 7
// 225.100 us; speedup vs baseline: 1.4063x; 1.0175x over previous
//
#include <hip/hip_runtime.h>

#define N_NODES 100000
#define N_EDGES 1000000
#define DEG_CAP 64
#define OVF_CAP 4096
#define SPILL_CAP 4096

// binning geometry
#define BKT_SH 8
#define BKT_NODES 256            // nodes per bucket
#define NBKT 392                 // 392*256 = 100352 >= N_NODES
#define BKT_CAP 4096             // record capacity per bucket (mean ~2551)
#define BIN_CHUNK 4096           // edges per bin block
#define FIFO_CAP 32              // LDS fifo depth per bucket (mean ~10.4)

typedef __attribute__((ext_vector_type(8))) short bf16x8;
typedef __attribute__((ext_vector_type(4))) float f32x4;

__device__ __forceinline__ unsigned short f2bf(float f) {
    unsigned u = __float_as_uint(f);
    return (unsigned short)((u + 0x7FFF + ((u >> 16) & 1)) >> 16);
}
__device__ __forceinline__ float bf2f(unsigned short b) {
    return __uint_as_float(((unsigned)b) << 16);
}
__device__ __forceinline__ float bflo(unsigned u) {   // low bf16 of a dword
    return __uint_as_float(u << 16);
}
__device__ __forceinline__ float bfhi(unsigned u) {   // high bf16 of a dword
    return __uint_as_float(u & 0xffff0000u);
}

// ws layout (4B units) — IDENTICAL to the round-5 passing version:
//   counts : [0, 100352)
//   ovfc 100352 ; spillc 100353
//   gcur   : [100416, 100928)
//   ovf    : [100928, 109120)
//   spill  : [109120, 117312)
//   Bf1    : s16 [117312, 133696)
//   Bf2    : s16 [133696, 150080)
//   slots  : [150080, 6572608)        100352*64 dwords
//   rec    : u32 [6572608, 8178240)
//   xb     : u16 [8178240, 11378240)  N*64 bf16
//   mean1  : f32 [11378240, 17778240) N*64
//   p_bf   : u16 [17778240, 20978240) own region (no mean1 alias: the fused
//                                     kernel reads mean1 cross-block)
//   q      : f32 [30578240, 36978240) N*64
// total 36,978,240 dwords = 147.9 MB

// Merged init + weight-split + x->bf16 (one launch).
__global__ __launch_bounds__(256) void prep_kernel(
        const float4* __restrict__ x4, ushort4* __restrict__ xb4,
        const float* __restrict__ W1l, const float* __restrict__ W1r,
        const float* __restrict__ W2l, const float* __restrict__ W2r,
        short* __restrict__ Bf1, short* __restrict__ Bf2,
        int4* __restrict__ gcur4, int* __restrict__ ovfc,
        int* __restrict__ spillc) {
    int i = blockIdx.x * blockDim.x + threadIdx.x;
    if (i < 128) gcur4[i] = make_int4(0, 0, 0, 0);
    if (i == 0) { *ovfc = 0; *spillc = 0; }
    if (i < 32768) {
        int g = i >> 14;
        int e = i & 16383;
        int k = e >> 7;
        int n = e & 127;
        float v;
        if (g == 0) v = (k < 64) ? W1l[k * 128 + n] : W1r[(k - 64) * 128 + n];
        else        v = (n < 64) ? W2l[k * 64 + n]  : W2r[k * 64 + (n - 64)];
        unsigned u = __float_as_uint(v);
        unsigned hb = u >> 16;
        float vh = __uint_as_float(hb << 16);
        unsigned lb = __float_as_uint(v - vh) >> 16;
        int c = n >> 4, kc = k >> 5;
        int lane = (((k >> 3) & 3) << 4) | (n & 15);
        int j = k & 7;
        short* base = g ? Bf2 : Bf1;
        base[((c * 4 + kc) * 2 + 0) * 512 + lane * 8 + j] = (short)hb;
        base[((c * 4 + kc) * 2 + 1) * 512 + lane * 8 + j] = (short)lb;
    }
    if (i < N_NODES * 16) {
        float4 v = x4[i];
        ushort4 o;
        o.x = f2bf(v.x); o.y = f2bf(v.y); o.z = f2bf(v.z); o.w = f2bf(v.w);
        xb4[i] = o;
    }
}

// Pass A: bin edges into 392 dst-range buckets via LDS FIFOs.
__global__ __launch_bounds__(256) void bin_kernel(
        const int* __restrict__ ei, unsigned* __restrict__ rec,
        int* __restrict__ gcur, int* __restrict__ spillc,
        int2* __restrict__ spill) {
    __shared__ int lcnt[NBKT];
    __shared__ unsigned fifo[NBKT * FIFO_CAP];   // 50KB
    for (int i = threadIdx.x; i < NBKT; i += 256) lcnt[i] = 0;
    __syncthreads();
    int base = blockIdx.x * BIN_CHUNK;
    int end = base + BIN_CHUNK;
    if (end > N_EDGES) end = N_EDGES;
    for (int e = base + threadIdx.x; e < end; e += 256) {
        int s = ei[e];
        int d = ei[N_EDGES + e];
        int b = d >> BKT_SH;
        unsigned r = ((unsigned)s << BKT_SH) | (unsigned)(d & (BKT_NODES - 1));
        int pos = atomicAdd(&lcnt[b], 1);
        if (pos < FIFO_CAP) {
            fifo[b * FIFO_CAP + pos] = r;
        } else {
            int o = atomicAdd(spillc, 1);
            if (o < SPILL_CAP) spill[o] = make_int2(s, d);
        }
    }
    __syncthreads();
    for (int b = threadIdx.x; b < NBKT; b += 256) {
        int cnt = lcnt[b];
        if (cnt > FIFO_CAP) cnt = FIFO_CAP;
        if (cnt == 0) continue;
        int gb = atomicAdd(&gcur[b], cnt);
        for (int k = 0; k < cnt; ++k) {
            int g = gb + k;
            unsigned r = fifo[b * FIFO_CAP + k];
            if (g < BKT_CAP) {
                rec[b * BKT_CAP + g] = r;
            } else {
                int o = atomicAdd(spillc, 1);
                if (o < SPILL_CAP)
                    spill[o] = make_int2((int)(r >> BKT_SH),
                                         (b << BKT_SH) | (int)(r & (BKT_NODES - 1)));
            }
        }
    }
}

// Pass B: one block per bucket; counts + slots tile built in LDS (65KB),
// written out fully coalesced.
__global__ __launch_bounds__(256) void build_kernel(
        const unsigned* __restrict__ rec, const int* __restrict__ gcur,
        int* __restrict__ counts, int* __restrict__ slots,
        int* __restrict__ ovfc, int* __restrict__ ovf) {
    __shared__ int lcnt[BKT_NODES];
    __shared__ int lslots[BKT_NODES * DEG_CAP];   // 64KB
    int b = blockIdx.x;
    for (int i = threadIdx.x; i < BKT_NODES; i += 256) lcnt[i] = 0;
    __syncthreads();
    int n = gcur[b];
    if (n > BKT_CAP) n = BKT_CAP;
    for (int i = threadIdx.x; i < n; i += 256) {
        unsigned r = rec[b * BKT_CAP + i];
        int dlo = (int)(r & (BKT_NODES - 1));
        int src = (int)(r >> BKT_SH);
        int pos = atomicAdd(&lcnt[dlo], 1);
        if (pos < DEG_CAP) {
            lslots[dlo * DEG_CAP + pos] = src;
        } else {
            int o = atomicAdd(ovfc, 1);
            if (o < OVF_CAP) {
                ovf[o * 2] = src;
                ovf[o * 2 + 1] = (b << BKT_SH) | dlo;
            }
        }
    }
    __syncthreads();
    int nodeBase = b << BKT_SH;
    for (int i = threadIdx.x; i < BKT_NODES; i += 256)
        counts[nodeBase + i] = lcnt[i];
    const int4* ls4 = (const int4*)lslots;
    int4* gs4 = (int4*)(slots + nodeBase * DEG_CAP);
    for (int i = threadIdx.x; i < BKT_NODES * DEG_CAP / 4; i += 256)
        gs4[i] = ls4[i];
}

// Rare-path spill fix-up.
__global__ __launch_bounds__(64) void spill_fix_kernel(
        const int2* __restrict__ spill, const int* __restrict__ spillc,
        int* __restrict__ counts, int* __restrict__ slots,
        int* __restrict__ ovfc, int* __restrict__ ovf) {
    int n = *spillc;
    if (n > SPILL_CAP) n = SPILL_CAP;
    int i = blockIdx.x * 64 + threadIdx.x;
    if (i >= n) return;
    int s = spill[i].x;
    int d = spill[i].y;
    int pos = atomicAdd(&counts[d], 1);
    if (pos < DEG_CAP) {
        slots[d * DEG_CAP + pos] = s;
    } else {
        int o = atomicAdd(ovfc, 1);
        if (o < OVF_CAP) { ovf[o * 2] = s; ovf[o * 2 + 1] = d; }
    }
}

// One wave per node. Lane l: neighbor subgroup l>>4, features (l&15)*4..+3.
__global__ __launch_bounds__(256) void gather_bf_kernel(
        const unsigned short* __restrict__ feat, const int* __restrict__ counts,
        const int* __restrict__ slots, float* __restrict__ agg) {
    int wid = blockIdx.x * 4 + (threadIdx.x >> 6);
    int l = threadIdx.x & 63;
    if (wid >= N_NODES) return;
    int deg = counts[wid];
    int dcap = min(deg, DEG_CAP);
    int ids = slots[wid * DEG_CAP + l];
    const int grp = l >> 4;
    const int fb = (l & 15) * 4;
    float s0 = 0.f, s1 = 0.f, s2 = 0.f, s3 = 0.f;
    int j = 0;
    for (; j + 8 <= dcap; j += 8) {
        int sA = __shfl(ids, j + grp);
        int sB = __shfl(ids, j + 4 + grp);
        uint2 uA = *(const uint2*)(feat + sA * 64 + fb);
        uint2 uB = *(const uint2*)(feat + sB * 64 + fb);
        s0 += bflo(uA.x) + bflo(uB.x);
        s1 += bfhi(uA.x) + bfhi(uB.x);
        s2 += bflo(uA.y) + bflo(uB.y);
        s3 += bfhi(uA.y) + bfhi(uB.y);
    }
    for (; j < dcap; j += 4) {
        int nb = j + grp;
        bool v = nb < dcap;
        int s = __shfl(ids, v ? nb : 0);
        uint2 u = *(const uint2*)(feat + s * 64 + fb);
        if (v) {
            s0 += bflo(u.x);
            s1 += bfhi(u.x);
            s2 += bflo(u.y);
            s3 += bfhi(u.y);
        }
    }
    s0 += __shfl_xor(s0, 16); s0 += __shfl_xor(s0, 32);
    s1 += __shfl_xor(s1, 16); s1 += __shfl_xor(s1, 32);
    s2 += __shfl_xor(s2, 16); s2 += __shfl_xor(s2, 32);
    s3 += __shfl_xor(s3, 16); s3 += __shfl_xor(s3, 32);
    if (l < 16) {
        float inv = 1.0f / fmaxf((float)deg, 1.0f);
        *(float4*)&agg[wid * 64 + fb] =
            make_float4(s0 * inv, s1 * inv, s2 * inv, s3 * inv);
    }
}

// Layer-1 overflow: add x*inv into mean.
__global__ __launch_bounds__(64) void ovf_scatter_kernel(
        const float* __restrict__ feat, const int* __restrict__ ovf,
        const int* __restrict__ ovfc, const int* __restrict__ counts,
        float* __restrict__ agg) {
    int n = *ovfc;
    if (n > OVF_CAP) n = OVF_CAP;
    for (int idx = blockIdx.x; idx < n; idx += gridDim.x) {
        int s = ovf[idx * 2];
        int d = ovf[idx * 2 + 1];
        float inv = 1.0f / fmaxf((float)counts[d], 1.0f);
        atomicAdd(&agg[d * 64 + threadIdx.x], feat[s * 64 + threadIdx.x] * inv);
    }
}

// FUSED MLP, 64-row tiles (grid 1563 -> ~6 blocks/CU vs 3 at 128-row:
// doubles latency-hiding wave count; bit-identical numerics to the
// passing 128-row version). h staged in LDS as bf16; phase 2 reads it
// with ds_read_b128 and needs no fp32->bf16 split.
__global__ __launch_bounds__(256) void mlp_fused_kernel(
        const float* __restrict__ mean1, const float* __restrict__ x,
        const short* __restrict__ Bf1, const float* __restrict__ b1,
        const short* __restrict__ Bf2, const float* __restrict__ b2,
        unsigned short* __restrict__ p_bf, float* __restrict__ q) {
    __shared__ unsigned short h_lds[64][136];   // 17408 B
    const int w = threadIdx.x >> 6;
    const int l = threadIdx.x & 63;
    const int lane15 = l & 15;
    const int quad = l >> 4;
    const int rowBase = blockIdx.x * 64;

    // ---- phase 1: layer 1, B-stationary, 3-MFMA hi/lo split ----
    {
        bf16x8 bh[2][4], bl[2][4];
#pragma unroll
        for (int ci = 0; ci < 2; ++ci) {
            const int c = 2 * w + ci;
#pragma unroll
            for (int kc = 0; kc < 4; ++kc) {
                const short* bp = Bf1 + ((c * 4 + kc) * 2) * 512 + l * 8;
                bh[ci][kc] = *(const bf16x8*)bp;
                bl[ci][kc] = *(const bf16x8*)(bp + 512);
            }
        }
        float bias[2];
#pragma unroll
        for (int ci = 0; ci < 2; ++ci) bias[ci] = b1[(2 * w + ci) * 16 + lane15];

#pragma unroll
        for (int rt = 0; rt < 4; ++rt) {
            const int row = rowBase + rt * 16 + lane15;
            const bool rv = row < N_NODES;

            bf16x8 ah[4], al[4];
#pragma unroll
            for (int kc = 0; kc < 4; ++kc) {
                float4 v0 = make_float4(0.f, 0.f, 0.f, 0.f);
                float4 v1 = make_float4(0.f, 0.f, 0.f, 0.f);
                if (rv) {
                    const float* src = (kc < 2)
                        ? (mean1 + row * 64 + kc * 32 + quad * 8)
                        : (x     + row * 64 + (kc - 2) * 32 + quad * 8);
                    v0 = *(const float4*)src;
                    v1 = *(const float4*)(src + 4);
                }
                float f[8] = {v0.x, v0.y, v0.z, v0.w, v1.x, v1.y, v1.z, v1.w};
#pragma unroll
                for (int j = 0; j < 8; ++j) {
                    unsigned u = __float_as_uint(f[j]);
                    unsigned hb = u >> 16;
                    float fh = __uint_as_float(hb << 16);
                    unsigned lb = __float_as_uint(f[j] - fh) >> 16;
                    ah[kc][j] = (short)hb;
                    al[kc][j] = (short)lb;
                }
            }

            f32x4 acc[2] = {(f32x4){0.f, 0.f, 0.f, 0.f}, (f32x4){0.f, 0.f, 0.f, 0.f}};
#pragma unroll
            for (int kc = 0; kc < 4; ++kc) {
#pragma unroll
                for (int ci = 0; ci < 2; ++ci) {
                    acc[ci] = __builtin_amdgcn_mfma_f32_16x16x32_bf16(ah[kc], bh[ci][kc], acc[ci], 0, 0, 0);
                    acc[ci] = __builtin_amdgcn_mfma_f32_16x16x32_bf16(al[kc], bh[ci][kc], acc[ci], 0, 0, 0);
                    acc[ci] = __builtin_amdgcn_mfma_f32_16x16x32_bf16(ah[kc], bl[ci][kc], acc[ci], 0, 0, 0);
                }
            }

            const int rloc = rt * 16 + quad * 4;
#pragma unroll
            for (int ci = 0; ci < 2; ++ci) {
                const int col = (2 * w + ci) * 16 + lane15;
#pragma unroll
                for (int i = 0; i < 4; ++i)
                    h_lds[rloc + i][col] =
                        f2bf(fmaxf(acc[ci][i] + bias[ci], 0.f));
            }
        }
    }
    __syncthreads();

    // ---- phase 2: layer 2 from LDS (A = bf16, W2 keeps hi/lo split) ----
    {
        bf16x8 bh[2][4], bl[2][4];
#pragma unroll
        for (int ci = 0; ci < 2; ++ci) {
            const int c = 2 * w + ci;
#pragma unroll
            for (int kc = 0; kc < 4; ++kc) {
                const short* bp = Bf2 + ((c * 4 + kc) * 2) * 512 + l * 8;
                bh[ci][kc] = *(const bf16x8*)bp;
                bl[ci][kc] = *(const bf16x8*)(bp + 512);
            }
        }
        float bias[2];
#pragma unroll
        for (int ci = 0; ci < 2; ++ci) {
            const int c = 2 * w + ci;
            bias[ci] = (c >= 4) ? b2[(c - 4) * 16 + lane15] : 0.f;
        }

#pragma unroll
        for (int rt = 0; rt < 4; ++rt) {
            bf16x8 ah[4];
#pragma unroll
            for (int kc = 0; kc < 4; ++kc)
                ah[kc] = *(const bf16x8*)&h_lds[rt * 16 + lane15][kc * 32 + quad * 8];

            f32x4 acc[2] = {(f32x4){0.f, 0.f, 0.f, 0.f}, (f32x4){0.f, 0.f, 0.f, 0.f}};
#pragma unroll
            for (int kc = 0; kc < 4; ++kc) {
#pragma unroll
                for (int ci = 0; ci < 2; ++ci) {
                    acc[ci] = __builtin_amdgcn_mfma_f32_16x16x32_bf16(ah[kc], bh[ci][kc], acc[ci], 0, 0, 0);
                    acc[ci] = __builtin_amdgcn_mfma_f32_16x16x32_bf16(ah[kc], bl[ci][kc], acc[ci], 0, 0, 0);
                }
            }

            const int rb = rowBase + rt * 16 + quad * 4;
#pragma unroll
            for (int ci = 0; ci < 2; ++ci) {
                const int c = 2 * w + ci;
                if (c < 4) {
#pragma unroll
                    for (int i = 0; i < 4; ++i) {
                        int r = rb + i;
                        if (r < N_NODES)
                            p_bf[r * 64 + c * 16 + lane15] = f2bf(acc[ci][i]);
                    }
                } else {
#pragma unroll
                    for (int i = 0; i < 4; ++i) {
                        int r = rb + i;
                        if (r < N_NODES)
                            q[r * 64 + (c - 4) * 16 + lane15] = acc[ci][i] + bias[ci];
                    }
                }
            }
        }
    }
}

// Fused layer-2 aggregation + epilogue: out = mean(p_bf[nbrs]) + q
__global__ __launch_bounds__(256) void gather_final_kernel(
        const unsigned short* __restrict__ p, const int* __restrict__ counts,
        const int* __restrict__ slots, const float* __restrict__ q,
        float* __restrict__ out) {
    int wid = blockIdx.x * 4 + (threadIdx.x >> 6);
    int l = threadIdx.x & 63;
    if (wid >= N_NODES) return;
    int deg = counts[wid];
    int dcap = min(deg, DEG_CAP);
    int ids = slots[wid * DEG_CAP + l];
    const int grp = l >> 4;
    const int fb = (l & 15) * 4;
    float s0 = 0.f, s1 = 0.f, s2 = 0.f, s3 = 0.f;
    int j = 0;
    for (; j + 8 <= dcap; j += 8) {
        int sA = __shfl(ids, j + grp);
        int sB = __shfl(ids, j + 4 + grp);
        uint2 uA = *(const uint2*)(p + sA * 64 + fb);
        uint2 uB = *(const uint2*)(p + sB * 64 + fb);
        s0 += bflo(uA.x) + bflo(uB.x);
        s1 += bfhi(uA.x) + bfhi(uB.x);
        s2 += bflo(uA.y) + bflo(uB.y);
        s3 += bfhi(uA.y) + bfhi(uB.y);
    }
    for (; j < dcap; j += 4) {
        int nb = j + grp;
        bool v = nb < dcap;
        int s = __shfl(ids, v ? nb : 0);
        uint2 u = *(const uint2*)(p + s * 64 + fb);
        if (v) {
            s0 += bflo(u.x);
            s1 += bfhi(u.x);
            s2 += bflo(u.y);
            s3 += bfhi(u.y);
        }
    }
    s0 += __shfl_xor(s0, 16); s0 += __shfl_xor(s0, 32);
    s1 += __shfl_xor(s1, 16); s1 += __shfl_xor(s1, 32);
    s2 += __shfl_xor(s2, 16); s2 += __shfl_xor(s2, 32);
    s3 += __shfl_xor(s3, 16); s3 += __shfl_xor(s3, 32);
    if (l < 16) {
        float inv = 1.0f / fmaxf((float)deg, 1.0f);
        float4 qv = *(const float4*)&q[wid * 64 + fb];
        *(float4*)&out[wid * 64 + fb] =
            make_float4(s0 * inv + qv.x, s1 * inv + qv.y,
                        s2 * inv + qv.z, s3 * inv + qv.w);
    }
}

// Layer-2 overflow fix-up (additive).
__global__ __launch_bounds__(64) void ovf_fixup_kernel(
        const unsigned short* __restrict__ p, const int* __restrict__ ovf,
        const int* __restrict__ ovfc, const int* __restrict__ counts,
        float* __restrict__ out) {
    int n = *ovfc;
    if (n > OVF_CAP) n = OVF_CAP;
    for (int idx = blockIdx.x; idx < n; idx += gridDim.x) {
        int s = ovf[idx * 2];
        int d = ovf[idx * 2 + 1];
        float inv = 1.0f / fmaxf((float)counts[d], 1.0f);
        atomicAdd(&out[d * 64 + threadIdx.x],
                  bf2f(p[s * 64 + threadIdx.x]) * inv);
    }
}

extern "C" void kernel_launch(void* const* d_in, const int* in_sizes, int n_in,
                              void* d_out, int out_size, void* d_ws, size_t ws_size,
                              hipStream_t stream) {
    const float* x   = (const float*)d_in[0];
    const float* W1l = (const float*)d_in[1];
    const float* W1r = (const float*)d_in[2];
    const float* b1  = (const float*)d_in[3];
    const float* W2l = (const float*)d_in[4];
    const float* W2r = (const float*)d_in[5];
    const float* b2  = (const float*)d_in[6];
    const int*   ei  = (const int*)d_in[7];

    int*   wsi      = (int*)d_ws;
    float* wsf      = (float*)d_ws;
    int*   counts   = wsi;
    int*   ovfc     = wsi + 100352;
    int*   spillc   = wsi + 100353;
    int*   gcur     = wsi + 100416;
    int*   ovf      = wsi + 100928;
    int2*  spill    = (int2*)(wsi + 109120);
    short* Bf1      = (short*)(wsi + 117312);
    short* Bf2      = (short*)(wsi + 133696);
    int*   slots    = wsi + 150080;
    unsigned* rec   = (unsigned*)(wsi + 6572608);
    unsigned short* xb = (unsigned short*)(wsi + 8178240);
    float* mean1    = wsf + 11378240;
    unsigned short* p_bf = (unsigned short*)(wsf + 17778240);  // own region!
    float* q        = wsf + 30578240;
    float* out      = (float*)d_out;

    prep_kernel<<<(N_NODES * 16 + 255) / 256, 256, 0, stream>>>(
        (const float4*)x, (ushort4*)xb, W1l, W1r, W2l, W2r,
        Bf1, Bf2, (int4*)gcur, ovfc, spillc);

    // indexing: LDS-binned two-pass
    bin_kernel<<<(N_EDGES + BIN_CHUNK - 1) / BIN_CHUNK, 256, 0, stream>>>(
        ei, rec, gcur, spillc, spill);
    build_kernel<<<NBKT, 256, 0, stream>>>(rec, gcur, counts, slots, ovfc, ovf);
    spill_fix_kernel<<<SPILL_CAP / 64, 64, 0, stream>>>(
        spill, spillc, counts, slots, ovfc, ovf);

    // layer-1 aggregation -> mean (fp32), + overflow
    gather_bf_kernel<<<(N_NODES + 3) / 4, 256, 0, stream>>>(
        xb, counts, slots, mean1);
    ovf_scatter_kernel<<<64, 64, 0, stream>>>(x, ovf, ovfc, counts, mean1);

    // fused MLP: h (LDS) -> p_bf, q in one pass (64-row tiles)
    mlp_fused_kernel<<<(N_NODES + 63) / 64, 256, 0, stream>>>(
        mean1, x, Bf1, b1, Bf2, b2, p_bf, q);

    // fused layer-2 aggregation + epilogue, then overflow fix-up
    gather_final_kernel<<<(N_NODES + 3) / 4, 256, 0, stream>>>(
        p_bf, counts, slots, q, out);
    ovf_fixup_kernel<<<64, 64, 0, stream>>>(p_bf, ovf, ovfc, counts, out);
}